// Round 1
// baseline (209.569 us; speedup 1.0000x reference)
//
#include <hip/hip_runtime.h>
#include <math.h>

// Problem constants
#define N_BATCH 64
#define CIN 256
#define CR 128
#define T_IN 8
#define H_IN 16
#define W_IN 16
#define S1 2048          // T_IN*H_IN*W_IN
#define T2 4
#define H2 8
#define W2 8
#define S2 256           // T2*H2*W2
#define PT 4
#define PH 7
#define PW 7
#define EPSB 1e-5f

__device__ __forceinline__ float hswish(float y) {
    float c = fminf(fmaxf(y + 3.0f, 0.0f), 6.0f);
    return y * c * (1.0f / 6.0f);
}

// ---------------------------------------------------------------------------
// Kernel A: 1x1x1 conv CIN=256 -> CR=128 + BN1 + hswish
// GEMM per n: h1[co,s] = sum_ci w1[co,ci] * x[n,ci,s]
// Block: 128 co x 128 s tile, 256 threads, 8x8 outputs/thread.
// ---------------------------------------------------------------------------
#define KC 16
__global__ __launch_bounds__(256) void conv1_kernel(
    const float* __restrict__ x, const float* __restrict__ w1,
    const float* __restrict__ g, const float* __restrict__ b,
    const float* __restrict__ m, const float* __restrict__ v,
    float* __restrict__ h1)
{
    __shared__ float Xs[KC][128];
    __shared__ float Ws[KC][CR + 4];   // transposed w tile, padded row

    int blk = blockIdx.x;
    int n  = blk >> 4;            // 16 s-tiles per n
    int s0 = (blk & 15) << 7;     // * 128
    int tid = threadIdx.x;
    int tco = tid >> 4;           // 0..15 -> 8 co each
    int ts  = tid & 15;           // 0..15 -> 8 s each
    const float* xn = x + (size_t)n * CIN * S1;

    float acc[8][8];
    #pragma unroll
    for (int i = 0; i < 8; i++)
        #pragma unroll
        for (int j = 0; j < 8; j++) acc[i][j] = 0.0f;

    for (int k0 = 0; k0 < CIN; k0 += KC) {
        // stage X tile: 16 k-rows x 128 s, float4 loads
        #pragma unroll
        for (int r = 0; r < 2; r++) {
            int e  = (tid + r * 256) * 4;        // 0..2044
            int kk = e >> 7;
            int ss = e & 127;
            float4 xv = *reinterpret_cast<const float4*>(xn + (size_t)(k0 + kk) * S1 + s0 + ss);
            *reinterpret_cast<float4*>(&Xs[kk][ss]) = xv;
        }
        // stage W tile transposed: Ws[kk][co] = w1[co*CIN + k0 + kk]
        #pragma unroll
        for (int r = 0; r < 8; r++) {
            int e  = tid + r * 256;              // 0..2047
            int co = e >> 4;
            int kk = e & 15;
            Ws[kk][co] = w1[co * CIN + k0 + kk];
        }
        __syncthreads();
        #pragma unroll
        for (int kk = 0; kk < KC; kk++) {
            float a[8], bb[8];
            #pragma unroll
            for (int r = 0; r < 8; r++) a[r] = Ws[kk][tco * 8 + r];
            #pragma unroll
            for (int q = 0; q < 8; q++) bb[q] = Xs[kk][ts * 8 + q];
            #pragma unroll
            for (int r = 0; r < 8; r++)
                #pragma unroll
                for (int q = 0; q < 8; q++)
                    acc[r][q] = fmaf(a[r], bb[q], acc[r][q]);
        }
        __syncthreads();
    }

    // epilogue: BN + hswish, vectorized store
    #pragma unroll
    for (int r = 0; r < 8; r++) {
        int co = tco * 8 + r;
        float sc = g[co] * rsqrtf(v[co] + EPSB);
        float tt = fmaf(-m[co], sc, b[co]);
        float* o = h1 + ((size_t)n * CR + co) * S1 + s0 + ts * 8;
        float4 o0, o1;
        o0.x = hswish(fmaf(acc[r][0], sc, tt));
        o0.y = hswish(fmaf(acc[r][1], sc, tt));
        o0.z = hswish(fmaf(acc[r][2], sc, tt));
        o0.w = hswish(fmaf(acc[r][3], sc, tt));
        o1.x = hswish(fmaf(acc[r][4], sc, tt));
        o1.y = hswish(fmaf(acc[r][5], sc, tt));
        o1.z = hswish(fmaf(acc[r][6], sc, tt));
        o1.w = hswish(fmaf(acc[r][7], sc, tt));
        *reinterpret_cast<float4*>(o)     = o0;
        *reinterpret_cast<float4*>(o + 4) = o1;
    }
}

// ---------------------------------------------------------------------------
// Kernel B: depthwise 3x3x3 conv stride 2 pad 1 + BN2 + hswish
// One block per (n,c); stage the [8][16][16] slice in LDS; 1 output/thread.
// ---------------------------------------------------------------------------
__global__ __launch_bounds__(256) void dwconv_kernel(
    const float* __restrict__ h1, const float* __restrict__ wdw,
    const float* __restrict__ g, const float* __restrict__ b,
    const float* __restrict__ m, const float* __restrict__ v,
    float* __restrict__ h2)
{
    __shared__ float s[T_IN][H_IN][W_IN];
    __shared__ float wl[27];
    int blk = blockIdx.x;
    int n = blk >> 7;
    int c = blk & 127;
    int tid = threadIdx.x;
    const float* in = h1 + ((size_t)n * CR + c) * S1;

    #pragma unroll
    for (int r = 0; r < 2; r++) {
        int e = (tid + r * 256) * 4;
        *reinterpret_cast<float4*>(&s[0][0][0] + e) =
            *reinterpret_cast<const float4*>(in + e);
    }
    if (tid < 27) wl[tid] = wdw[c * 27 + tid];
    __syncthreads();

    int wo = tid & 7;
    int ho = (tid >> 3) & 7;
    int to = tid >> 6;
    float acc = 0.0f;
    #pragma unroll
    for (int dt = 0; dt < 3; dt++) {
        int ti = 2 * to - 1 + dt;
        if (ti < 0 || ti >= T_IN) continue;
        #pragma unroll
        for (int dh = 0; dh < 3; dh++) {
            int hi = 2 * ho - 1 + dh;
            if (hi < 0 || hi >= H_IN) continue;
            #pragma unroll
            for (int dw = 0; dw < 3; dw++) {
                int wi = 2 * wo - 1 + dw;
                if (wi < 0 || wi >= W_IN) continue;
                acc = fmaf(wl[(dt * 3 + dh) * 3 + dw], s[ti][hi][wi], acc);
            }
        }
    }
    float sc = g[c] * rsqrtf(v[c] + EPSB);
    float y  = fmaf(acc, sc, fmaf(-m[c], sc, b[c]));
    h2[((size_t)n * CR + c) * S2 + tid] = hswish(y);
}

// ---------------------------------------------------------------------------
// Kernel C: 1x1x1 conv 128 -> 128 + BN3 + hswish on [64,128,256]
// Block: 128 co x 64 s tile, 256 threads, 4x8 outputs/thread.
// ---------------------------------------------------------------------------
__global__ __launch_bounds__(256) void conv2_kernel(
    const float* __restrict__ h2, const float* __restrict__ w2,
    const float* __restrict__ g, const float* __restrict__ b,
    const float* __restrict__ m, const float* __restrict__ v,
    float* __restrict__ h3)
{
    __shared__ float Xs[KC][64];
    __shared__ float Ws[KC][CR + 4];

    int blk = blockIdx.x;
    int n  = blk >> 2;           // 4 s-tiles per n
    int s0 = (blk & 3) << 6;
    int tid = threadIdx.x;
    int tco = tid >> 3;          // 0..31 -> 4 co each
    int ts  = tid & 7;           // 0..7  -> 8 s each
    const float* xn = h2 + (size_t)n * CR * S2;

    float acc[4][8];
    #pragma unroll
    for (int i = 0; i < 4; i++)
        #pragma unroll
        for (int j = 0; j < 8; j++) acc[i][j] = 0.0f;

    for (int k0 = 0; k0 < CR; k0 += KC) {
        {
            int e  = tid * 4;            // 0..1020
            int kk = e >> 6;
            int ss = e & 63;
            float4 xv = *reinterpret_cast<const float4*>(xn + (size_t)(k0 + kk) * S2 + s0 + ss);
            *reinterpret_cast<float4*>(&Xs[kk][ss]) = xv;
        }
        #pragma unroll
        for (int r = 0; r < 8; r++) {
            int e  = tid + r * 256;
            int co = e >> 4;
            int kk = e & 15;
            Ws[kk][co] = w2[co * CR + k0 + kk];
        }
        __syncthreads();
        #pragma unroll
        for (int kk = 0; kk < KC; kk++) {
            float a[4], bb[8];
            #pragma unroll
            for (int r = 0; r < 4; r++) a[r] = Ws[kk][tco * 4 + r];
            #pragma unroll
            for (int q = 0; q < 8; q++) bb[q] = Xs[kk][ts * 8 + q];
            #pragma unroll
            for (int r = 0; r < 4; r++)
                #pragma unroll
                for (int q = 0; q < 8; q++)
                    acc[r][q] = fmaf(a[r], bb[q], acc[r][q]);
        }
        __syncthreads();
    }

    #pragma unroll
    for (int r = 0; r < 4; r++) {
        int co = tco * 4 + r;
        float sc = g[co] * rsqrtf(v[co] + EPSB);
        float tt = fmaf(-m[co], sc, b[co]);
        float* o = h3 + ((size_t)n * CR + co) * S2 + s0 + ts * 8;
        float4 o0, o1;
        o0.x = hswish(fmaf(acc[r][0], sc, tt));
        o0.y = hswish(fmaf(acc[r][1], sc, tt));
        o0.z = hswish(fmaf(acc[r][2], sc, tt));
        o0.w = hswish(fmaf(acc[r][3], sc, tt));
        o1.x = hswish(fmaf(acc[r][4], sc, tt));
        o1.y = hswish(fmaf(acc[r][5], sc, tt));
        o1.z = hswish(fmaf(acc[r][6], sc, tt));
        o1.w = hswish(fmaf(acc[r][7], sc, tt));
        *reinterpret_cast<float4*>(o)     = o0;
        *reinterpret_cast<float4*>(o + 4) = o1;
    }
}

// ---------------------------------------------------------------------------
// Kernel D: global mean over the 256 spatial positions -> pooled[n][c]
// One block per n; 4 waves, each wave handles 32 channels.
// ---------------------------------------------------------------------------
__global__ __launch_bounds__(256) void pool_kernel(
    const float* __restrict__ h3, float* __restrict__ pooled)
{
    int n = blockIdx.x;
    int tid = threadIdx.x;
    int wave = tid >> 6;
    int lane = tid & 63;
    for (int i = 0; i < 32; i++) {
        int c = wave * 32 + i;
        const float* p = h3 + ((size_t)n * CR + c) * S2;
        float sum = p[lane] + p[lane + 64] + p[lane + 128] + p[lane + 192];
        #pragma unroll
        for (int off = 32; off > 0; off >>= 1)
            sum += __shfl_down(sum, off, 64);
        if (lane == 0) pooled[n * CR + c] = sum * (1.0f / 256.0f);
    }
}

// ---------------------------------------------------------------------------
// Kernel E: head — 1x1 conv 128->6 + BN4 + sigmoid -> ROI boxes [n][6]
// boxes: start_x, start_y, start_t, end_x, end_y, end_t
// ---------------------------------------------------------------------------
__global__ __launch_bounds__(384) void head_kernel(
    const float* __restrict__ pooled, const float* __restrict__ w3,
    const float* __restrict__ g, const float* __restrict__ b,
    const float* __restrict__ m, const float* __restrict__ v,
    float* __restrict__ boxes)
{
    int tid = threadIdx.x;      // 0..383
    int n = tid / 6;
    int j = tid % 6;
    float acc = 0.0f;
    for (int c = 0; c < CR; c++)
        acc = fmaf(w3[j * CR + c], pooled[n * CR + c], acc);
    float sc = g[j] * rsqrtf(v[j] + EPSB);
    float logit = fmaf(acc, sc, fmaf(-m[j], sc, b[j]));
    float lim = 1.0f / (1.0f + expf(-logit));
    // scales = (W, H, T) = (16, 16, 8), dims in (x, y, t) order
    float scale = ((j % 3) == 2) ? 8.0f : 16.0f;
    float val = (j < 3) ? 0.5f * lim * scale : (1.0f - 0.5f * lim) * scale;
    boxes[n * 6 + j] = val;
}

// ---------------------------------------------------------------------------
// Kernel F: 3D ROI align of x.  One block per (n,c); slice in LDS.
// out[n,c,pt,ph,pw], OUT_SIZE=(4,7,7), RS=2 samples/bin/dim, trilinear.
// ---------------------------------------------------------------------------
__global__ __launch_bounds__(256) void roi_kernel(
    const float* __restrict__ x, const float* __restrict__ boxes,
    float* __restrict__ out)
{
    __shared__ float s[T_IN][H_IN][W_IN];
    __shared__ float box[6];
    int blk = blockIdx.x;
    int n = blk >> 8;
    int c = blk & 255;
    int tid = threadIdx.x;
    const float* in = x + ((size_t)n * CIN + c) * S1;
    #pragma unroll
    for (int r = 0; r < 2; r++) {
        int e = (tid + r * 256) * 4;
        *reinterpret_cast<float4*>(&s[0][0][0] + e) =
            *reinterpret_cast<const float4*>(in + e);
    }
    if (tid < 6) box[tid] = boxes[n * 6 + tid];
    __syncthreads();

    if (tid < PT * PH * PW) {
        int pw = tid % 7;
        int ph = (tid / 7) % 7;
        int pt = tid / 49;
        float sx = box[0], sy = box[1], st = box[2];
        float bszx = fmaxf(box[3] - sx, 1.0f) * (1.0f / PW);
        float bszy = fmaxf(box[4] - sy, 1.0f) * (1.0f / PH);
        float bszt = fmaxf(box[5] - st, 1.0f) * (1.0f / PT);

        float acc = 0.0f;
        #pragma unroll
        for (int it = 0; it < 2; it++) {
            float tc = st + ((float)(pt * 2 + it) + 0.5f) * 0.5f * bszt;
            tc = fminf(fmaxf(tc, 0.0f), (float)(T_IN - 1));
            int tlo = (int)floorf(tc);
            int thi = min(tlo + 1, T_IN - 1);
            float tw = tc - (float)tlo;
            #pragma unroll
            for (int iy = 0; iy < 2; iy++) {
                float yc = sy + ((float)(ph * 2 + iy) + 0.5f) * 0.5f * bszy;
                yc = fminf(fmaxf(yc, 0.0f), (float)(H_IN - 1));
                int ylo = (int)floorf(yc);
                int yhi = min(ylo + 1, H_IN - 1);
                float yw = yc - (float)ylo;
                #pragma unroll
                for (int ix = 0; ix < 2; ix++) {
                    float xc = sx + ((float)(pw * 2 + ix) + 0.5f) * 0.5f * bszx;
                    xc = fminf(fmaxf(xc, 0.0f), (float)(W_IN - 1));
                    int xlo = (int)floorf(xc);
                    int xhi = min(xlo + 1, W_IN - 1);
                    float xw = xc - (float)xlo;

                    float v00 = s[tlo][ylo][xlo] * (1.0f - xw) + s[tlo][ylo][xhi] * xw;
                    float v01 = s[tlo][yhi][xlo] * (1.0f - xw) + s[tlo][yhi][xhi] * xw;
                    float v10 = s[thi][ylo][xlo] * (1.0f - xw) + s[thi][ylo][xhi] * xw;
                    float v11 = s[thi][yhi][xlo] * (1.0f - xw) + s[thi][yhi][xhi] * xw;
                    float v0 = v00 * (1.0f - yw) + v01 * yw;
                    float v1 = v10 * (1.0f - yw) + v11 * yw;
                    acc += v0 * (1.0f - tw) + v1 * tw;
                }
            }
        }
        out[(((size_t)(n * CIN + c) * PT + pt) * PH + ph) * PW + pw] = acc * 0.125f;
    }
}

// ---------------------------------------------------------------------------
extern "C" void kernel_launch(void* const* d_in, const int* in_sizes, int n_in,
                              void* d_out, int out_size, void* d_ws, size_t ws_size,
                              hipStream_t stream) {
    const float* x   = (const float*)d_in[0];
    const float* w1  = (const float*)d_in[1];
    const float* g1  = (const float*)d_in[2];
    const float* b1  = (const float*)d_in[3];
    const float* m1  = (const float*)d_in[4];
    const float* v1  = (const float*)d_in[5];
    const float* wdw = (const float*)d_in[6];
    const float* g2  = (const float*)d_in[7];
    const float* b2  = (const float*)d_in[8];
    const float* m2  = (const float*)d_in[9];
    const float* v2  = (const float*)d_in[10];
    const float* w2  = (const float*)d_in[11];
    const float* g3  = (const float*)d_in[12];
    const float* b3  = (const float*)d_in[13];
    const float* m3  = (const float*)d_in[14];
    const float* v3  = (const float*)d_in[15];
    const float* w3  = (const float*)d_in[16];
    const float* g4  = (const float*)d_in[17];
    const float* b4  = (const float*)d_in[18];
    const float* m4  = (const float*)d_in[19];
    const float* v4  = (const float*)d_in[20];

    float* ws = (float*)d_ws;
    float* h1     = ws;                          // 64*128*2048 = 16,777,216
    float* h2     = h1 + (size_t)N_BATCH * CR * S1;       // 2,097,152
    float* h3     = h2 + (size_t)N_BATCH * CR * S2;       // 2,097,152
    float* pooled = h3 + (size_t)N_BATCH * CR * S2;       // 8,192
    float* boxes  = pooled + (size_t)N_BATCH * CR;        // 384

    conv1_kernel<<<dim3(1024), dim3(256), 0, stream>>>(x, w1, g1, b1, m1, v1, h1);
    dwconv_kernel<<<dim3(N_BATCH * CR), dim3(256), 0, stream>>>(h1, wdw, g2, b2, m2, v2, h2);
    conv2_kernel<<<dim3(256), dim3(256), 0, stream>>>(h2, w2, g3, b3, m3, v3, h3);
    pool_kernel<<<dim3(N_BATCH), dim3(256), 0, stream>>>(h3, pooled);
    head_kernel<<<dim3(1), dim3(384), 0, stream>>>(pooled, w3, g4, b4, m4, v4, boxes);
    roi_kernel<<<dim3(N_BATCH * CIN), dim3(256), 0, stream>>>(x, boxes, (float*)d_out);
}

// Round 2
// 160.369 us; speedup vs baseline: 1.3068x; 1.3068x over previous
//
#include <hip/hip_runtime.h>
#include <math.h>

// Problem constants
#define N_BATCH 64
#define CIN 256
#define CR 128
#define T_IN 8
#define H_IN 16
#define W_IN 16
#define S1 2048          // T_IN*H_IN*W_IN
#define T2 4
#define H2 8
#define W2 8
#define S2 256           // T2*H2*W2
#define PT 4
#define PH 7
#define PW 7
#define EPSB 1e-5f

typedef __attribute__((ext_vector_type(8))) short bf16x8;
typedef __attribute__((ext_vector_type(4))) float f32x4;

__device__ __forceinline__ float hswish(float y) {
    float c = fminf(fmaxf(y + 3.0f, 0.0f), 6.0f);
    return y * c * (1.0f / 6.0f);
}

__device__ __forceinline__ unsigned int fbits(float x) {
    return __float_as_uint(x);
}

// ---------------------------------------------------------------------------
// Prep: split w1 (fp32 [128][256]) into bf16 hi/lo arrays.
// ---------------------------------------------------------------------------
__global__ __launch_bounds__(256) void wsplit_kernel(
    const float* __restrict__ w1, unsigned short* __restrict__ whi,
    unsigned short* __restrict__ wlo)
{
    int i = blockIdx.x * 256 + threadIdx.x;   // 0..32767
    float x = w1[i];
    unsigned int bx = fbits(x);
    unsigned int h = (bx + 0x8000u) & 0xFFFF0000u;
    float r = x - __uint_as_float(h);
    whi[i] = (unsigned short)(h >> 16);
    wlo[i] = (unsigned short)((fbits(r) + 0x8000u) >> 16);
}

// ---------------------------------------------------------------------------
// Kernel A: 1x1x1 conv CIN=256 -> CR=128 + BN1 + hswish, via split-bf16 MFMA.
// Per block: 128co x 128s output tile, 4 waves (2x2), each wave 64x64 (4x4
// fragments of 16x16).  K staged in 4 steps of 64, X transposed into LDS
// [s][k] bf16 hi/lo with XOR swizzle on the 16B slot: slot ^= (s&7).
// ---------------------------------------------------------------------------
__global__ __launch_bounds__(256) void conv1_mfma_kernel(
    const float* __restrict__ x,
    const unsigned short* __restrict__ whi, const unsigned short* __restrict__ wlo,
    const float* __restrict__ g, const float* __restrict__ b,
    const float* __restrict__ m, const float* __restrict__ v,
    float* __restrict__ h1)
{
    __shared__ unsigned int XtH[4096];   // [128 s][64 k] bf16 = 32 u32/row
    __shared__ unsigned int XtL[4096];
    __shared__ float scs[CR];
    __shared__ float tts[CR];

    int blk = blockIdx.x;
    int n  = blk >> 4;
    int s0 = (blk & 15) << 7;
    int tid = threadIdx.x;
    int wave = tid >> 6;
    int lane = tid & 63;
    int gl   = lane >> 4;     // 0..3  (k-chunk / C-row group)
    int ln16 = lane & 15;
    const float* xn = x + (size_t)n * CIN * S1;

    if (tid < CR) {
        float sc = g[tid] * rsqrtf(v[tid] + EPSB);
        scs[tid] = sc;
        tts[tid] = fmaf(-m[tid], sc, b[tid]);
    }

    int wco = (wave >> 1) * 64;   // wave's co base within [0,128)
    int wss = (wave & 1) * 64;    // wave's s base within tile [0,128)

    // staging assignment: thread handles k rows {2kp, 2kp+1}, s = 2mm+e+16j
    int kp = tid >> 3;            // 0..31
    int mm = tid & 7;

    f32x4 acc[4][4];
    #pragma unroll
    for (int i = 0; i < 4; i++)
        #pragma unroll
        for (int j = 0; j < 4; j++)
            acc[i][j] = (f32x4){0.f, 0.f, 0.f, 0.f};

    float2 st[16];
    // prologue loads for ks=0
    #pragma unroll
    for (int kk = 0; kk < 2; kk++)
        #pragma unroll
        for (int j = 0; j < 8; j++)
            st[kk * 8 + j] = *reinterpret_cast<const float2*>(
                xn + (size_t)(2 * kp + kk) * S1 + s0 + 2 * mm + 16 * j);

    for (int ks = 0; ks < 4; ++ks) {
        // convert + transposed swizzled LDS write
        #pragma unroll
        for (int j = 0; j < 8; j++) {
            #pragma unroll
            for (int e = 0; e < 2; e++) {
                float x0 = e ? st[j].y : st[j].x;          // k = 2kp
                float x1 = e ? st[8 + j].y : st[8 + j].x;  // k = 2kp+1
                unsigned int b0 = fbits(x0), b1 = fbits(x1);
                unsigned int h0 = (b0 + 0x8000u) & 0xFFFF0000u;
                unsigned int h1b = (b1 + 0x8000u) & 0xFFFF0000u;
                float r0 = x0 - __uint_as_float(h0);
                float r1 = x1 - __uint_as_float(h1b);
                unsigned int hip_ = (h0 >> 16) | h1b;
                unsigned int lop_ = ((fbits(r0) + 0x8000u) >> 16) |
                                    ((fbits(r1) + 0x8000u) & 0xFFFF0000u);
                int s = 2 * mm + e + 16 * j;
                int idx = s * 32 + ((((kp >> 2) ^ (s & 7)) << 2) | (kp & 3));
                XtH[idx] = hip_;
                XtL[idx] = lop_;
            }
        }
        __syncthreads();

        // prefetch next K-step's X while MFMAs run
        if (ks < 3) {
            int k0n = (ks + 1) * 64;
            #pragma unroll
            for (int kk = 0; kk < 2; kk++)
                #pragma unroll
                for (int j = 0; j < 8; j++)
                    st[kk * 8 + j] = *reinterpret_cast<const float2*>(
                        xn + (size_t)(k0n + 2 * kp + kk) * S1 + s0 + 2 * mm + 16 * j);
        }

        int k0 = ks * 64;
        #pragma unroll
        for (int r = 0; r < 2; r++) {
            bf16x8 Ah[4], Al[4];
            #pragma unroll
            for (int fc = 0; fc < 4; fc++) {
                int co = wco + fc * 16 + ln16;
                size_t off = (size_t)co * CIN + k0 + r * 32 + gl * 8;
                Ah[fc] = *reinterpret_cast<const bf16x8*>(whi + off);
                Al[fc] = *reinterpret_cast<const bf16x8*>(wlo + off);
            }
            #pragma unroll
            for (int fs = 0; fs < 4; fs++) {
                int s = wss + fs * 16 + ln16;
                int idx = s * 32 + (((((r << 2) | gl) ^ (s & 7)) << 2));
                bf16x8 Bh = *reinterpret_cast<bf16x8*>(&XtH[idx]);
                bf16x8 Bl = *reinterpret_cast<bf16x8*>(&XtL[idx]);
                #pragma unroll
                for (int fc = 0; fc < 4; fc++) {
                    acc[fc][fs] = __builtin_amdgcn_mfma_f32_16x16x32_bf16(
                        Ah[fc], Bh, acc[fc][fs], 0, 0, 0);
                    acc[fc][fs] = __builtin_amdgcn_mfma_f32_16x16x32_bf16(
                        Ah[fc], Bl, acc[fc][fs], 0, 0, 0);
                    acc[fc][fs] = __builtin_amdgcn_mfma_f32_16x16x32_bf16(
                        Al[fc], Bh, acc[fc][fs], 0, 0, 0);
                }
            }
        }
        __syncthreads();
    }

    // epilogue: BN + hswish + store
    #pragma unroll
    for (int fc = 0; fc < 4; fc++) {
        #pragma unroll
        for (int reg = 0; reg < 4; reg++) {
            int co = wco + fc * 16 + gl * 4 + reg;
            float sc = scs[co];
            float tt = tts[co];
            #pragma unroll
            for (int fs = 0; fs < 4; fs++) {
                int s = s0 + wss + fs * 16 + ln16;
                float y = hswish(fmaf(acc[fc][fs][reg], sc, tt));
                h1[((size_t)n * CR + co) * S1 + s] = y;
            }
        }
    }
}

// ---------------------------------------------------------------------------
// Kernel B: depthwise 3x3x3 conv stride 2 pad 1 + BN2 + hswish
// ---------------------------------------------------------------------------
__global__ __launch_bounds__(256) void dwconv_kernel(
    const float* __restrict__ h1, const float* __restrict__ wdw,
    const float* __restrict__ g, const float* __restrict__ b,
    const float* __restrict__ m, const float* __restrict__ v,
    float* __restrict__ h2)
{
    __shared__ float s[T_IN][H_IN][W_IN];
    __shared__ float wl[27];
    int blk = blockIdx.x;
    int n = blk >> 7;
    int c = blk & 127;
    int tid = threadIdx.x;
    const float* in = h1 + ((size_t)n * CR + c) * S1;

    #pragma unroll
    for (int r = 0; r < 2; r++) {
        int e = (tid + r * 256) * 4;
        *reinterpret_cast<float4*>(&s[0][0][0] + e) =
            *reinterpret_cast<const float4*>(in + e);
    }
    if (tid < 27) wl[tid] = wdw[c * 27 + tid];
    __syncthreads();

    int wo = tid & 7;
    int ho = (tid >> 3) & 7;
    int to = tid >> 6;
    float acc = 0.0f;
    #pragma unroll
    for (int dt = 0; dt < 3; dt++) {
        int ti = 2 * to - 1 + dt;
        if (ti < 0 || ti >= T_IN) continue;
        #pragma unroll
        for (int dh = 0; dh < 3; dh++) {
            int hi = 2 * ho - 1 + dh;
            if (hi < 0 || hi >= H_IN) continue;
            #pragma unroll
            for (int dw = 0; dw < 3; dw++) {
                int wi = 2 * wo - 1 + dw;
                if (wi < 0 || wi >= W_IN) continue;
                acc = fmaf(wl[(dt * 3 + dh) * 3 + dw], s[ti][hi][wi], acc);
            }
        }
    }
    float sc = g[c] * rsqrtf(v[c] + EPSB);
    float y  = fmaf(acc, sc, fmaf(-m[c], sc, b[c]));
    h2[((size_t)n * CR + c) * S2 + tid] = hswish(y);
}

// ---------------------------------------------------------------------------
// Kernel C: 1x1x1 conv 128 -> 128 + BN3 + hswish on [64,128,256]
// ---------------------------------------------------------------------------
#define KC 16
__global__ __launch_bounds__(256) void conv2_kernel(
    const float* __restrict__ h2, const float* __restrict__ w2,
    const float* __restrict__ g, const float* __restrict__ b,
    const float* __restrict__ m, const float* __restrict__ v,
    float* __restrict__ h3)
{
    __shared__ float Xs[KC][64];
    __shared__ float Ws[KC][CR + 4];

    int blk = blockIdx.x;
    int n  = blk >> 2;
    int s0 = (blk & 3) << 6;
    int tid = threadIdx.x;
    int tco = tid >> 3;
    int ts  = tid & 7;
    const float* xn = h2 + (size_t)n * CR * S2;

    float acc[4][8];
    #pragma unroll
    for (int i = 0; i < 4; i++)
        #pragma unroll
        for (int j = 0; j < 8; j++) acc[i][j] = 0.0f;

    for (int k0 = 0; k0 < CR; k0 += KC) {
        {
            int e  = tid * 4;
            int kk = e >> 6;
            int ss = e & 63;
            float4 xv = *reinterpret_cast<const float4*>(xn + (size_t)(k0 + kk) * S2 + s0 + ss);
            *reinterpret_cast<float4*>(&Xs[kk][ss]) = xv;
        }
        #pragma unroll
        for (int r = 0; r < 8; r++) {
            int e  = tid + r * 256;
            int co = e >> 4;
            int kk = e & 15;
            Ws[kk][co] = w2[co * CR + k0 + kk];
        }
        __syncthreads();
        #pragma unroll
        for (int kk = 0; kk < KC; kk++) {
            float a[4], bb[8];
            #pragma unroll
            for (int r = 0; r < 4; r++) a[r] = Ws[kk][tco * 4 + r];
            #pragma unroll
            for (int q = 0; q < 8; q++) bb[q] = Xs[kk][ts * 8 + q];
            #pragma unroll
            for (int r = 0; r < 4; r++)
                #pragma unroll
                for (int q = 0; q < 8; q++)
                    acc[r][q] = fmaf(a[r], bb[q], acc[r][q]);
        }
        __syncthreads();
    }

    #pragma unroll
    for (int r = 0; r < 4; r++) {
        int co = tco * 4 + r;
        float sc = g[co] * rsqrtf(v[co] + EPSB);
        float tt = fmaf(-m[co], sc, b[co]);
        float* o = h3 + ((size_t)n * CR + co) * S2 + s0 + ts * 8;
        float4 o0, o1;
        o0.x = hswish(fmaf(acc[r][0], sc, tt));
        o0.y = hswish(fmaf(acc[r][1], sc, tt));
        o0.z = hswish(fmaf(acc[r][2], sc, tt));
        o0.w = hswish(fmaf(acc[r][3], sc, tt));
        o1.x = hswish(fmaf(acc[r][4], sc, tt));
        o1.y = hswish(fmaf(acc[r][5], sc, tt));
        o1.z = hswish(fmaf(acc[r][6], sc, tt));
        o1.w = hswish(fmaf(acc[r][7], sc, tt));
        *reinterpret_cast<float4*>(o)     = o0;
        *reinterpret_cast<float4*>(o + 4) = o1;
    }
}

// ---------------------------------------------------------------------------
// Kernel D: global mean over 256 spatial positions -> pooled[n][c]
// ---------------------------------------------------------------------------
__global__ __launch_bounds__(256) void pool_kernel(
    const float* __restrict__ h3, float* __restrict__ pooled)
{
    int n = blockIdx.x;
    int tid = threadIdx.x;
    int wave = tid >> 6;
    int lane = tid & 63;
    for (int i = 0; i < 32; i++) {
        int c = wave * 32 + i;
        const float* p = h3 + ((size_t)n * CR + c) * S2;
        float sum = p[lane] + p[lane + 64] + p[lane + 128] + p[lane + 192];
        #pragma unroll
        for (int off = 32; off > 0; off >>= 1)
            sum += __shfl_down(sum, off, 64);
        if (lane == 0) pooled[n * CR + c] = sum * (1.0f / 256.0f);
    }
}

// ---------------------------------------------------------------------------
// Kernel E: head — 1x1 conv 128->6 + BN4 + sigmoid -> ROI boxes [n][6]
// ---------------------------------------------------------------------------
__global__ __launch_bounds__(384) void head_kernel(
    const float* __restrict__ pooled, const float* __restrict__ w3,
    const float* __restrict__ g, const float* __restrict__ b,
    const float* __restrict__ m, const float* __restrict__ v,
    float* __restrict__ boxes)
{
    int tid = threadIdx.x;      // 0..383
    int n = tid / 6;
    int j = tid % 6;
    float acc = 0.0f;
    for (int c = 0; c < CR; c++)
        acc = fmaf(w3[j * CR + c], pooled[n * CR + c], acc);
    float sc = g[j] * rsqrtf(v[j] + EPSB);
    float logit = fmaf(acc, sc, fmaf(-m[j], sc, b[j]));
    float lim = 1.0f / (1.0f + expf(-logit));
    float scale = ((j % 3) == 2) ? 8.0f : 16.0f;
    float val = (j < 3) ? 0.5f * lim * scale : (1.0f - 0.5f * lim) * scale;
    boxes[n * 6 + j] = val;
}

// ---------------------------------------------------------------------------
// Kernel F: 3D ROI align of x.  One block per (n,c); slice in LDS.
// ---------------------------------------------------------------------------
__global__ __launch_bounds__(256) void roi_kernel(
    const float* __restrict__ x, const float* __restrict__ boxes,
    float* __restrict__ out)
{
    __shared__ float s[T_IN][H_IN][W_IN];
    __shared__ float box[6];
    int blk = blockIdx.x;
    int n = blk >> 8;
    int c = blk & 255;
    int tid = threadIdx.x;
    const float* in = x + ((size_t)n * CIN + c) * S1;
    #pragma unroll
    for (int r = 0; r < 2; r++) {
        int e = (tid + r * 256) * 4;
        *reinterpret_cast<float4*>(&s[0][0][0] + e) =
            *reinterpret_cast<const float4*>(in + e);
    }
    if (tid < 6) box[tid] = boxes[n * 6 + tid];
    __syncthreads();

    if (tid < PT * PH * PW) {
        int pw = tid % 7;
        int ph = (tid / 7) % 7;
        int pt = tid / 49;
        float sx = box[0], sy = box[1], st = box[2];
        float bszx = fmaxf(box[3] - sx, 1.0f) * (1.0f / PW);
        float bszy = fmaxf(box[4] - sy, 1.0f) * (1.0f / PH);
        float bszt = fmaxf(box[5] - st, 1.0f) * (1.0f / PT);

        float acc = 0.0f;
        #pragma unroll
        for (int it = 0; it < 2; it++) {
            float tc = st + ((float)(pt * 2 + it) + 0.5f) * 0.5f * bszt;
            tc = fminf(fmaxf(tc, 0.0f), (float)(T_IN - 1));
            int tlo = (int)floorf(tc);
            int thi = min(tlo + 1, T_IN - 1);
            float tw = tc - (float)tlo;
            #pragma unroll
            for (int iy = 0; iy < 2; iy++) {
                float yc = sy + ((float)(ph * 2 + iy) + 0.5f) * 0.5f * bszy;
                yc = fminf(fmaxf(yc, 0.0f), (float)(H_IN - 1));
                int ylo = (int)floorf(yc);
                int yhi = min(ylo + 1, H_IN - 1);
                float yw = yc - (float)ylo;
                #pragma unroll
                for (int ix = 0; ix < 2; ix++) {
                    float xc = sx + ((float)(pw * 2 + ix) + 0.5f) * 0.5f * bszx;
                    xc = fminf(fmaxf(xc, 0.0f), (float)(W_IN - 1));
                    int xlo = (int)floorf(xc);
                    int xhi = min(xlo + 1, W_IN - 1);
                    float xw = xc - (float)xlo;

                    float v00 = s[tlo][ylo][xlo] * (1.0f - xw) + s[tlo][ylo][xhi] * xw;
                    float v01 = s[tlo][yhi][xlo] * (1.0f - xw) + s[tlo][yhi][xhi] * xw;
                    float v10 = s[thi][ylo][xlo] * (1.0f - xw) + s[thi][ylo][xhi] * xw;
                    float v11 = s[thi][yhi][xlo] * (1.0f - xw) + s[thi][yhi][xhi] * xw;
                    float v0 = v00 * (1.0f - yw) + v01 * yw;
                    float v1 = v10 * (1.0f - yw) + v11 * yw;
                    acc += v0 * (1.0f - tw) + v1 * tw;
                }
            }
        }
        out[(((size_t)(n * CIN + c) * PT + pt) * PH + ph) * PW + pw] = acc * 0.125f;
    }
}

// ---------------------------------------------------------------------------
extern "C" void kernel_launch(void* const* d_in, const int* in_sizes, int n_in,
                              void* d_out, int out_size, void* d_ws, size_t ws_size,
                              hipStream_t stream) {
    const float* x   = (const float*)d_in[0];
    const float* w1  = (const float*)d_in[1];
    const float* g1  = (const float*)d_in[2];
    const float* b1  = (const float*)d_in[3];
    const float* m1  = (const float*)d_in[4];
    const float* v1  = (const float*)d_in[5];
    const float* wdw = (const float*)d_in[6];
    const float* g2  = (const float*)d_in[7];
    const float* b2  = (const float*)d_in[8];
    const float* m2  = (const float*)d_in[9];
    const float* v2  = (const float*)d_in[10];
    const float* w2  = (const float*)d_in[11];
    const float* g3  = (const float*)d_in[12];
    const float* b3  = (const float*)d_in[13];
    const float* m3  = (const float*)d_in[14];
    const float* v3  = (const float*)d_in[15];
    const float* w3  = (const float*)d_in[16];
    const float* g4  = (const float*)d_in[17];
    const float* b4  = (const float*)d_in[18];
    const float* m4  = (const float*)d_in[19];
    const float* v4  = (const float*)d_in[20];

    float* ws = (float*)d_ws;
    float* h1     = ws;                                   // 16,777,216 f
    float* h2     = h1 + (size_t)N_BATCH * CR * S1;       //  2,097,152 f
    float* h3     = h2 + (size_t)N_BATCH * CR * S2;       //  2,097,152 f
    float* pooled = h3 + (size_t)N_BATCH * CR * S2;       //      8,192 f
    float* boxes  = pooled + (size_t)N_BATCH * CR;        //        384 f
    // whi/wlo live in the h3 region: written by wsplit before conv1 runs,
    // consumed only by conv1; h3 itself is written later by conv2.
    unsigned short* whi = (unsigned short*)h3;            // 32768 u16
    unsigned short* wlo = whi + CR * CIN;                 // 32768 u16

    wsplit_kernel<<<dim3(128), dim3(256), 0, stream>>>(w1, whi, wlo);
    conv1_mfma_kernel<<<dim3(1024), dim3(256), 0, stream>>>(x, whi, wlo, g1, b1, m1, v1, h1);
    dwconv_kernel<<<dim3(N_BATCH * CR), dim3(256), 0, stream>>>(h1, wdw, g2, b2, m2, v2, h2);
    conv2_kernel<<<dim3(256), dim3(256), 0, stream>>>(h2, w2, g3, b3, m3, v3, h3);
    pool_kernel<<<dim3(N_BATCH), dim3(256), 0, stream>>>(h3, pooled);
    head_kernel<<<dim3(1), dim3(384), 0, stream>>>(pooled, w3, g4, b4, m4, v4, boxes);
    roi_kernel<<<dim3(N_BATCH * CIN), dim3(256), 0, stream>>>(x, boxes, (float*)d_out);
}

// Round 6
// 154.329 us; speedup vs baseline: 1.3579x; 1.0391x over previous
//
#include <hip/hip_runtime.h>
#include <math.h>

// Problem constants
#define N_BATCH 64
#define CIN 256
#define CR 128
#define T_IN 8
#define H_IN 16
#define W_IN 16
#define S1 2048          // T_IN*H_IN*W_IN
#define T2 4
#define H2 8
#define W2 8
#define S2 256           // T2*H2*W2
#define PT 4
#define PH 7
#define PW 7
#define EPSB 1e-5f

typedef __attribute__((ext_vector_type(8))) short bf16x8;
typedef __attribute__((ext_vector_type(4))) float f32x4;
typedef __attribute__((ext_vector_type(4))) unsigned int u32x4;
typedef __attribute__((ext_vector_type(8))) unsigned short ushort8;

__device__ __forceinline__ float hswish(float y) {
    float c = fminf(fmaxf(y + 3.0f, 0.0f), 6.0f);
    return y * c * (1.0f / 6.0f);
}

__device__ __forceinline__ unsigned int fbits(float x) {
    return __float_as_uint(x);
}

// static-index helper for float4 components (folds under #pragma unroll)
__device__ __forceinline__ float f4c(const float4& v, int i) {
    return i == 0 ? v.x : (i == 1 ? v.y : (i == 2 ? v.z : v.w));
}

// ---------------------------------------------------------------------------
// Prep: split w1 (fp32 [128][256]) into bf16 hi/lo arrays.
// ---------------------------------------------------------------------------
__global__ __launch_bounds__(256) void wsplit_kernel(
    const float* __restrict__ w1, unsigned short* __restrict__ whi,
    unsigned short* __restrict__ wlo)
{
    int i = blockIdx.x * 256 + threadIdx.x;   // 0..32767
    float x = w1[i];
    unsigned int bx = fbits(x);
    unsigned int h = (bx + 0x8000u) & 0xFFFF0000u;
    float r = x - __uint_as_float(h);
    whi[i] = (unsigned short)(h >> 16);
    wlo[i] = (unsigned short)((fbits(r) + 0x8000u) >> 16);
}

// ---------------------------------------------------------------------------
// Kernel A v3: 1x1x1 conv 256->128 + BN1 + hswish, split-bf16 MFMA,
// NO LDS, NO barriers.  Block = 4 waves; wave w computes co [32w,32w+32)
// x s [s0, s0+64).  W fragments (hi+lo) preloaded to 128 VGPRs.
// B fragment column c of s-fragment fs maps to s = s0 + c*4 + fs, so each
// lane loads float4 (s0+ln16*4 ..+4) per k -- fully coalesced -- and the
// epilogue writes 4 consecutive bf16 per lane (8B packed stores).
// 2-term product: x~ (bf16) * (whi + wlo).
// ---------------------------------------------------------------------------
__global__ __launch_bounds__(256, 2) void conv1_mfma_kernel(
    const float* __restrict__ x,
    const unsigned short* __restrict__ whi, const unsigned short* __restrict__ wlo,
    const float* __restrict__ g, const float* __restrict__ b,
    const float* __restrict__ m, const float* __restrict__ v,
    unsigned short* __restrict__ h1b)
{
    int blk = blockIdx.x;
    int n  = blk >> 5;
    int s0 = (blk & 31) << 6;
    int tid = threadIdx.x;
    int wave = tid >> 6;
    int lane = tid & 63;
    int gl   = lane >> 4;
    int ln16 = lane & 15;
    int wco = wave * 32;
    const float* xs = x + (size_t)n * CIN * S1 + s0 + ln16 * 4;

    // ---- preload W fragments (one-time L2 gather) ----
    bf16x8 Ah[2][8], Al[2][8];
    #pragma unroll
    for (int fc = 0; fc < 2; fc++)
        #pragma unroll
        for (int kf = 0; kf < 8; kf++) {
            size_t off = (size_t)(wco + fc * 16 + ln16) * CIN + kf * 32 + gl * 8;
            Ah[fc][kf] = *reinterpret_cast<const bf16x8*>(whi + off);
            Al[fc][kf] = *reinterpret_cast<const bf16x8*>(wlo + off);
        }

    f32x4 acc[2][4];
    #pragma unroll
    for (int i = 0; i < 2; i++)
        #pragma unroll
        for (int j = 0; j < 4; j++)
            acc[i][j] = (f32x4){0.f, 0.f, 0.f, 0.f};

    float4 st[2][8];
    #pragma unroll
    for (int j = 0; j < 8; j++)
        st[0][j] = *reinterpret_cast<const float4*>(xs + (size_t)(gl * 8 + j) * S1);

    #pragma unroll
    for (int ks = 0; ks < 8; ks++) {
        // prefetch next K-step into the other buffer (static index: full unroll)
        if (ks < 7) {
            #pragma unroll
            for (int j = 0; j < 8; j++)
                st[(ks + 1) & 1][j] = *reinterpret_cast<const float4*>(
                    xs + (size_t)((ks + 1) * 32 + gl * 8 + j) * S1);
        }
        // convert current buffer -> 4 B-fragments (bf16)
        bf16x8 Bh[4];
        #pragma unroll
        for (int fs = 0; fs < 4; fs++) {
            union { u32x4 u; bf16x8 bv; } cv;
            #pragma unroll
            for (int p = 0; p < 4; p++) {
                unsigned int b0 = fbits(f4c(st[ks & 1][2 * p],     fs));
                unsigned int b1 = fbits(f4c(st[ks & 1][2 * p + 1], fs));
                cv.u[p] = ((b0 + 0x8000u) >> 16) | ((b1 + 0x8000u) & 0xFFFF0000u);
            }
            Bh[fs] = cv.bv;
        }
        // 16 MFMAs
        #pragma unroll
        for (int fs = 0; fs < 4; fs++)
            #pragma unroll
            for (int fc = 0; fc < 2; fc++) {
                acc[fc][fs] = __builtin_amdgcn_mfma_f32_16x16x32_bf16(
                    Ah[fc][ks], Bh[fs], acc[fc][fs], 0, 0, 0);
                acc[fc][fs] = __builtin_amdgcn_mfma_f32_16x16x32_bf16(
                    Al[fc][ks], Bh[fs], acc[fc][fs], 0, 0, 0);
            }
    }

    // ---- epilogue: BN + hswish + packed bf16 store (8B per lane per row) ----
    #pragma unroll
    for (int fc = 0; fc < 2; fc++)
        #pragma unroll
        for (int reg = 0; reg < 4; reg++) {
            int co = wco + fc * 16 + gl * 4 + reg;
            float sc = g[co] * rsqrtf(v[co] + EPSB);
            float tt = fmaf(-m[co], sc, b[co]);
            float y0 = hswish(fmaf(acc[fc][0][reg], sc, tt));
            float y1 = hswish(fmaf(acc[fc][1][reg], sc, tt));
            float y2 = hswish(fmaf(acc[fc][2][reg], sc, tt));
            float y3 = hswish(fmaf(acc[fc][3][reg], sc, tt));
            uint2 pk;
            pk.x = ((fbits(y0) + 0x8000u) >> 16) | ((fbits(y1) + 0x8000u) & 0xFFFF0000u);
            pk.y = ((fbits(y2) + 0x8000u) >> 16) | ((fbits(y3) + 0x8000u) & 0xFFFF0000u);
            *reinterpret_cast<uint2*>(
                h1b + ((size_t)n * CR + co) * S1 + s0 + ln16 * 4) = pk;
        }
}

// ---------------------------------------------------------------------------
// Kernel B: depthwise 3x3x3 conv stride 2 pad 1 + BN2 + hswish (bf16 input)
// ---------------------------------------------------------------------------
__global__ __launch_bounds__(256) void dwconv_kernel(
    const unsigned short* __restrict__ h1b, const float* __restrict__ wdw,
    const float* __restrict__ g, const float* __restrict__ b,
    const float* __restrict__ m, const float* __restrict__ v,
    float* __restrict__ h2)
{
    __shared__ float s[T_IN][H_IN][W_IN];
    __shared__ float wl[27];
    int blk = blockIdx.x;
    int n = blk >> 7;
    int c = blk & 127;
    int tid = threadIdx.x;
    const unsigned short* in = h1b + ((size_t)n * CR + c) * S1;

    {
        int e = tid * 8;
        ushort8 u = *reinterpret_cast<const ushort8*>(in + e);
        float* sp = &s[0][0][0] + e;
        #pragma unroll
        for (int i = 0; i < 8; i++)
            sp[i] = __uint_as_float((unsigned int)(unsigned short)u[i] << 16);
    }
    if (tid < 27) wl[tid] = wdw[c * 27 + tid];
    __syncthreads();

    int wo = tid & 7;
    int ho = (tid >> 3) & 7;
    int to = tid >> 6;
    float acc = 0.0f;
    #pragma unroll
    for (int dt = 0; dt < 3; dt++) {
        int ti = 2 * to - 1 + dt;
        if (ti < 0 || ti >= T_IN) continue;
        #pragma unroll
        for (int dh = 0; dh < 3; dh++) {
            int hi = 2 * ho - 1 + dh;
            if (hi < 0 || hi >= H_IN) continue;
            #pragma unroll
            for (int dw = 0; dw < 3; dw++) {
                int wi = 2 * wo - 1 + dw;
                if (wi < 0 || wi >= W_IN) continue;
                acc = fmaf(wl[(dt * 3 + dh) * 3 + dw], s[ti][hi][wi], acc);
            }
        }
    }
    float sc = g[c] * rsqrtf(v[c] + EPSB);
    float y  = fmaf(acc, sc, fmaf(-m[c], sc, b[c]));
    h2[((size_t)n * CR + c) * S2 + tid] = hswish(y);
}

// ---------------------------------------------------------------------------
// Kernel C: 1x1x1 conv 128 -> 128 + BN3 + hswish on [64,128,256]
// ---------------------------------------------------------------------------
#define KC 16
__global__ __launch_bounds__(256) void conv2_kernel(
    const float* __restrict__ h2, const float* __restrict__ w2,
    const float* __restrict__ g, const float* __restrict__ b,
    const float* __restrict__ m, const float* __restrict__ v,
    float* __restrict__ h3)
{
    __shared__ float Xs[KC][64];
    __shared__ float Ws[KC][CR + 4];

    int blk = blockIdx.x;
    int n  = blk >> 2;
    int s0 = (blk & 3) << 6;
    int tid = threadIdx.x;
    int tco = tid >> 3;
    int ts  = tid & 7;
    const float* xn = h2 + (size_t)n * CR * S2;

    float acc[4][8];
    #pragma unroll
    for (int i = 0; i < 4; i++)
        #pragma unroll
        for (int j = 0; j < 8; j++) acc[i][j] = 0.0f;

    for (int k0 = 0; k0 < CR; k0 += KC) {
        {
            int e  = tid * 4;
            int kk = e >> 6;
            int ss = e & 63;
            float4 xv = *reinterpret_cast<const float4*>(xn + (size_t)(k0 + kk) * S2 + s0 + ss);
            *reinterpret_cast<float4*>(&Xs[kk][ss]) = xv;
        }
        #pragma unroll
        for (int r = 0; r < 8; r++) {
            int e  = tid + r * 256;
            int co = e >> 4;
            int kk = e & 15;
            Ws[kk][co] = w2[co * CR + k0 + kk];
        }
        __syncthreads();
        #pragma unroll
        for (int kk = 0; kk < KC; kk++) {
            float a[4], bb[8];
            #pragma unroll
            for (int r = 0; r < 4; r++) a[r] = Ws[kk][tco * 4 + r];
            #pragma unroll
            for (int q = 0; q < 8; q++) bb[q] = Xs[kk][ts * 8 + q];
            #pragma unroll
            for (int r = 0; r < 4; r++)
                #pragma unroll
                for (int q = 0; q < 8; q++)
                    acc[r][q] = fmaf(a[r], bb[q], acc[r][q]);
        }
        __syncthreads();
    }

    #pragma unroll
    for (int r = 0; r < 4; r++) {
        int co = tco * 4 + r;
        float sc = g[co] * rsqrtf(v[co] + EPSB);
        float tt = fmaf(-m[co], sc, b[co]);
        float* o = h3 + ((size_t)n * CR + co) * S2 + s0 + ts * 8;
        float4 o0, o1;
        o0.x = hswish(fmaf(acc[r][0], sc, tt));
        o0.y = hswish(fmaf(acc[r][1], sc, tt));
        o0.z = hswish(fmaf(acc[r][2], sc, tt));
        o0.w = hswish(fmaf(acc[r][3], sc, tt));
        o1.x = hswish(fmaf(acc[r][4], sc, tt));
        o1.y = hswish(fmaf(acc[r][5], sc, tt));
        o1.z = hswish(fmaf(acc[r][6], sc, tt));
        o1.w = hswish(fmaf(acc[r][7], sc, tt));
        *reinterpret_cast<float4*>(o)     = o0;
        *reinterpret_cast<float4*>(o + 4) = o1;
    }
}

// ---------------------------------------------------------------------------
// Kernel D: global mean over 256 spatial positions -> pooled[n][c]
// ---------------------------------------------------------------------------
__global__ __launch_bounds__(256) void pool_kernel(
    const float* __restrict__ h3, float* __restrict__ pooled)
{
    int n = blockIdx.x;
    int tid = threadIdx.x;
    int wave = tid >> 6;
    int lane = tid & 63;
    for (int i = 0; i < 32; i++) {
        int c = wave * 32 + i;
        const float* p = h3 + ((size_t)n * CR + c) * S2;
        float sum = p[lane] + p[lane + 64] + p[lane + 128] + p[lane + 192];
        #pragma unroll
        for (int off = 32; off > 0; off >>= 1)
            sum += __shfl_down(sum, off, 64);
        if (lane == 0) pooled[n * CR + c] = sum * (1.0f / 256.0f);
    }
}

// ---------------------------------------------------------------------------
// Kernel E: head — 1x1 conv 128->6 + BN4 + sigmoid -> ROI boxes [n][6]
// ---------------------------------------------------------------------------
__global__ __launch_bounds__(384) void head_kernel(
    const float* __restrict__ pooled, const float* __restrict__ w3,
    const float* __restrict__ g, const float* __restrict__ b,
    const float* __restrict__ m, const float* __restrict__ v,
    float* __restrict__ boxes)
{
    int tid = threadIdx.x;      // 0..383
    int n = tid / 6;
    int j = tid % 6;
    float acc = 0.0f;
    for (int c = 0; c < CR; c++)
        acc = fmaf(w3[j * CR + c], pooled[n * CR + c], acc);
    float sc = g[j] * rsqrtf(v[j] + EPSB);
    float logit = fmaf(acc, sc, fmaf(-m[j], sc, b[j]));
    float lim = 1.0f / (1.0f + expf(-logit));
    float scale = ((j % 3) == 2) ? 8.0f : 16.0f;
    float val = (j < 3) ? 0.5f * lim * scale : (1.0f - 0.5f * lim) * scale;
    boxes[n * 6 + j] = val;
}

// ---------------------------------------------------------------------------
// Kernel F: 3D ROI align of x.  One block per (n,c); slice in LDS.
// ---------------------------------------------------------------------------
__global__ __launch_bounds__(256) void roi_kernel(
    const float* __restrict__ x, const float* __restrict__ boxes,
    float* __restrict__ out)
{
    __shared__ float s[T_IN][H_IN][W_IN];
    __shared__ float box[6];
    int blk = blockIdx.x;
    int n = blk >> 8;
    int c = blk & 255;
    int tid = threadIdx.x;
    const float* in = x + ((size_t)n * CIN + c) * S1;
    #pragma unroll
    for (int r = 0; r < 2; r++) {
        int e = (tid + r * 256) * 4;
        *reinterpret_cast<float4*>(&s[0][0][0] + e) =
            *reinterpret_cast<const float4*>(in + e);
    }
    if (tid < 6) box[tid] = boxes[n * 6 + tid];
    __syncthreads();

    if (tid < PT * PH * PW) {
        int pw = tid % 7;
        int ph = (tid / 7) % 7;
        int pt = tid / 49;
        float sx = box[0], sy = box[1], st = box[2];
        float bszx = fmaxf(box[3] - sx, 1.0f) * (1.0f / PW);
        float bszy = fmaxf(box[4] - sy, 1.0f) * (1.0f / PH);
        float bszt = fmaxf(box[5] - st, 1.0f) * (1.0f / PT);

        float acc = 0.0f;
        #pragma unroll
        for (int it = 0; it < 2; it++) {
            float tc = st + ((float)(pt * 2 + it) + 0.5f) * 0.5f * bszt;
            tc = fminf(fmaxf(tc, 0.0f), (float)(T_IN - 1));
            int tlo = (int)floorf(tc);
            int thi = min(tlo + 1, T_IN - 1);
            float tw = tc - (float)tlo;
            #pragma unroll
            for (int iy = 0; iy < 2; iy++) {
                float yc = sy + ((float)(ph * 2 + iy) + 0.5f) * 0.5f * bszy;
                yc = fminf(fmaxf(yc, 0.0f), (float)(H_IN - 1));
                int ylo = (int)floorf(yc);
                int yhi = min(ylo + 1, H_IN - 1);
                float yw = yc - (float)ylo;
                #pragma unroll
                for (int ix = 0; ix < 2; ix++) {
                    float xc = sx + ((float)(pw * 2 + ix) + 0.5f) * 0.5f * bszx;
                    xc = fminf(fmaxf(xc, 0.0f), (float)(W_IN - 1));
                    int xlo = (int)floorf(xc);
                    int xhi = min(xlo + 1, W_IN - 1);
                    float xw = xc - (float)xlo;

                    float v00 = s[tlo][ylo][xlo] * (1.0f - xw) + s[tlo][ylo][xhi] * xw;
                    float v01 = s[tlo][yhi][xlo] * (1.0f - xw) + s[tlo][yhi][xhi] * xw;
                    float v10 = s[thi][ylo][xlo] * (1.0f - xw) + s[thi][ylo][xhi] * xw;
                    float v11 = s[thi][yhi][xlo] * (1.0f - xw) + s[thi][yhi][xhi] * xw;
                    float v0 = v00 * (1.0f - yw) + v01 * yw;
                    float v1 = v10 * (1.0f - yw) + v11 * yw;
                    acc += v0 * (1.0f - tw) + v1 * tw;
                }
            }
        }
        out[(((size_t)(n * CIN + c) * PT + pt) * PH + ph) * PW + pw] = acc * 0.125f;
    }
}

// ---------------------------------------------------------------------------
extern "C" void kernel_launch(void* const* d_in, const int* in_sizes, int n_in,
                              void* d_out, int out_size, void* d_ws, size_t ws_size,
                              hipStream_t stream) {
    const float* x   = (const float*)d_in[0];
    const float* w1  = (const float*)d_in[1];
    const float* g1  = (const float*)d_in[2];
    const float* b1  = (const float*)d_in[3];
    const float* m1  = (const float*)d_in[4];
    const float* v1  = (const float*)d_in[5];
    const float* wdw = (const float*)d_in[6];
    const float* g2  = (const float*)d_in[7];
    const float* b2  = (const float*)d_in[8];
    const float* m2  = (const float*)d_in[9];
    const float* v2  = (const float*)d_in[10];
    const float* w2  = (const float*)d_in[11];
    const float* g3  = (const float*)d_in[12];
    const float* b3  = (const float*)d_in[13];
    const float* m3  = (const float*)d_in[14];
    const float* v3  = (const float*)d_in[15];
    const float* w3  = (const float*)d_in[16];
    const float* g4  = (const float*)d_in[17];
    const float* b4  = (const float*)d_in[18];
    const float* m4  = (const float*)d_in[19];
    const float* v4  = (const float*)d_in[20];

    float* ws = (float*)d_ws;
    float* h1     = ws;                                   // used as bf16 (ushort)
    float* h2     = h1 + (size_t)N_BATCH * CR * S1;       //  2,097,152 f
    float* h3     = h2 + (size_t)N_BATCH * CR * S2;       //  2,097,152 f
    float* pooled = h3 + (size_t)N_BATCH * CR * S2;       //      8,192 f
    float* boxes  = pooled + (size_t)N_BATCH * CR;        //        384 f
    unsigned short* h1b = (unsigned short*)h1;            // bf16 h1
    // whi/wlo live in the h3 region (h3 written later by conv2)
    unsigned short* whi = (unsigned short*)h3;            // 32768 u16
    unsigned short* wlo = whi + CR * CIN;                 // 32768 u16

    wsplit_kernel<<<dim3(128), dim3(256), 0, stream>>>(w1, whi, wlo);
    conv1_mfma_kernel<<<dim3(2048), dim3(256), 0, stream>>>(x, whi, wlo, g1, b1, m1, v1, h1b);
    dwconv_kernel<<<dim3(N_BATCH * CR), dim3(256), 0, stream>>>(h1b, wdw, g2, b2, m2, v2, h2);
    conv2_kernel<<<dim3(256), dim3(256), 0, stream>>>(h2, w2, g3, b3, m3, v3, h3);
    pool_kernel<<<dim3(N_BATCH), dim3(256), 0, stream>>>(h3, pooled);
    head_kernel<<<dim3(1), dim3(384), 0, stream>>>(pooled, w3, g4, b4, m4, v4, boxes);
    roi_kernel<<<dim3(N_BATCH * CIN), dim3(256), 0, stream>>>(x, boxes, (float*)d_out);
}

// Round 8
// 152.391 us; speedup vs baseline: 1.3752x; 1.0127x over previous
//
#include <hip/hip_runtime.h>
#include <math.h>

// Problem constants
#define N_BATCH 64
#define CIN 256
#define CR 128
#define T_IN 8
#define H_IN 16
#define W_IN 16
#define S1 2048          // T_IN*H_IN*W_IN
#define T2 4
#define H2 8
#define W2 8
#define S2 256           // T2*H2*W2
#define PT 4
#define PH 7
#define PW 7
#define EPSB 1e-5f

#define LDS_ROW 68       // words per k-row: 64 + 4 pad (keeps 16B alignment)

typedef __attribute__((ext_vector_type(8))) short bf16x8;
typedef __attribute__((ext_vector_type(4))) float f32x4;
typedef __attribute__((ext_vector_type(4))) unsigned int u32x4;
typedef __attribute__((ext_vector_type(8))) unsigned short ushort8;

__device__ __forceinline__ float hswish(float y) {
    float c = fminf(fmaxf(y + 3.0f, 0.0f), 6.0f);
    return y * c * (1.0f / 6.0f);
}

__device__ __forceinline__ unsigned int fbits(float x) {
    return __float_as_uint(x);
}

__device__ __forceinline__ unsigned int pkbf16(float lo, float hi) {
    return ((fbits(lo) + 0x8000u) >> 16) | ((fbits(hi) + 0x8000u) & 0xFFFF0000u);
}

// ---------------------------------------------------------------------------
// Prep: split w1 (fp32 [128][256]) into bf16 hi/lo in FRAGMENT-COALESCED
// layout: flat = ((((co>>4)*8 + (k>>5))*4 + ((k>>3)&3))*16 + (co&15))*8 + (k&7)
// so a wave's fragment load (coG, kf) is one contiguous 1KB block.
// ---------------------------------------------------------------------------
__global__ __launch_bounds__(256) void wsplit_kernel(
    const float* __restrict__ w1, unsigned short* __restrict__ whi,
    unsigned short* __restrict__ wlo)
{
    int i = blockIdx.x * 256 + threadIdx.x;   // 0..32767
    int co = i >> 8;
    int k  = i & 255;
    float x = w1[i];
    unsigned int bx = fbits(x);
    unsigned int h = (bx + 0x8000u) & 0xFFFF0000u;
    float r = x - __uint_as_float(h);
    int flat = ((((co >> 4) * 8 + (k >> 5)) * 4 + ((k >> 3) & 3)) * 16 + (co & 15)) * 8 + (k & 7);
    whi[flat] = (unsigned short)(h >> 16);
    wlo[flat] = (unsigned short)((fbits(r) + 0x8000u) >> 16);
}

// ---------------------------------------------------------------------------
// Kernel A v4: 1x1x1 conv 256->128 + BN1 + hswish, split-bf16 MFMA.
// Tile [128 co][64 s] per block, 4 waves (2 co-halves x 2 s-halves), each
// wave 64co x 32s (4 fc x 2 fs fragments).  K staged in 8 steps of 32:
// x staged ONCE per block to LDS (fp32, padded+XOR-swizzled, double-buffered);
// W loaded per K-step from the fragment-coalesced layout (1KB/wave-load).
// One barrier per K-step.  2-term product: x~(bf16) * (whi + wlo).
// ---------------------------------------------------------------------------
__global__ __launch_bounds__(256, 4) void conv1_mfma_kernel(
    const float* __restrict__ x,
    const unsigned short* __restrict__ whi, const unsigned short* __restrict__ wlo,
    const float* __restrict__ g, const float* __restrict__ b,
    const float* __restrict__ m, const float* __restrict__ v,
    unsigned short* __restrict__ h1b)
{
    __shared__ float X[2][32 * LDS_ROW];   // 2 x 8704B = 17.4 KB

    int blk = blockIdx.x;
    int n  = blk >> 5;
    int s0 = (blk & 31) << 6;
    int tid = threadIdx.x;
    int wave = tid >> 6;
    int lane = tid & 63;
    int gl   = lane >> 4;          // 0..3
    int ln16 = lane & 15;
    int wcoG = (wave >> 1) * 4;    // co-group base (16-co units): 0 or 4
    int wsl  = (wave & 1) * 32;    // s-local base: 0 or 32

    // --- staging thread coords: thread covers k-row kloc, quads qs, qs+1 ---
    int kloc = tid >> 3;           // 0..31
    int qs   = (tid & 7) * 2;      // 0,2,..,14
    const float* xg = x + (size_t)n * CIN * S1 + s0;
    int wofs0 = kloc * LDS_ROW + ((qs    ) ^ (kloc & 7)) * 4;
    int wofs1 = kloc * LDS_ROW + ((qs + 1) ^ (kloc & 7)) * 4;

    // --- LDS read offsets (words) per fragment element j ---
    int rq = (wsl >> 2) + (ln16 >> 1);        // unswizzled quad 0..15
    int rofs[8];
    #pragma unroll
    for (int j = 0; j < 8; j++)
        rofs[j] = (gl * 8 + j) * LDS_ROW + ((rq ^ j) * 4) + (ln16 & 1) * 2;

    f32x4 acc[4][2];
    #pragma unroll
    for (int i = 0; i < 4; i++) {
        acc[i][0] = (f32x4){0.f, 0.f, 0.f, 0.f};
        acc[i][1] = (f32x4){0.f, 0.f, 0.f, 0.f};
    }

    // --- prologue: stage K-step 0 ---
    {
        const float* p = xg + (size_t)kloc * S1 + qs * 4;
        float4 L0 = *reinterpret_cast<const float4*>(p);
        float4 L1 = *reinterpret_cast<const float4*>(p + 4);
        *reinterpret_cast<float4*>(&X[0][wofs0]) = L0;
        *reinterpret_cast<float4*>(&X[0][wofs1]) = L1;
    }
    __syncthreads();

    #pragma unroll
    for (int ks = 0; ks < 8; ks++) {
        // 1. prefetch next K-step's x into regs
        float4 P0, P1;
        if (ks < 7) {
            const float* p = xg + (size_t)((ks + 1) * 32 + kloc) * S1 + qs * 4;
            P0 = *reinterpret_cast<const float4*>(p);
            P1 = *reinterpret_cast<const float4*>(p + 4);
        }
        // 2. W fragment loads (coalesced 1KB per wave-instruction, L2-hot)
        bf16x8 Ah[4], Al[4];
        #pragma unroll
        for (int fc = 0; fc < 4; fc++) {
            int off = ((((wcoG + fc) * 8 + ks) * 4 + gl) * 16 + ln16) * 8;
            Ah[fc] = *reinterpret_cast<const bf16x8*>(whi + off);
            Al[fc] = *reinterpret_cast<const bf16x8*>(wlo + off);
        }
        // 3. LDS reads + convert -> two B fragments (fs=0,1)
        const float* Xb = X[ks & 1];
        float2 rd[8];
        #pragma unroll
        for (int j = 0; j < 8; j++)
            rd[j] = *reinterpret_cast<const float2*>(&Xb[rofs[j]]);
        union { u32x4 u; bf16x8 bv; } c0, c1;
        #pragma unroll
        for (int p = 0; p < 4; p++) {
            c0.u[p] = pkbf16(rd[2 * p].x, rd[2 * p + 1].x);
            c1.u[p] = pkbf16(rd[2 * p].y, rd[2 * p + 1].y);
        }
        // 4. 16 MFMAs
        #pragma unroll
        for (int fc = 0; fc < 4; fc++) {
            acc[fc][0] = __builtin_amdgcn_mfma_f32_16x16x32_bf16(Ah[fc], c0.bv, acc[fc][0], 0, 0, 0);
            acc[fc][0] = __builtin_amdgcn_mfma_f32_16x16x32_bf16(Al[fc], c0.bv, acc[fc][0], 0, 0, 0);
            acc[fc][1] = __builtin_amdgcn_mfma_f32_16x16x32_bf16(Ah[fc], c1.bv, acc[fc][1], 0, 0, 0);
            acc[fc][1] = __builtin_amdgcn_mfma_f32_16x16x32_bf16(Al[fc], c1.bv, acc[fc][1], 0, 0, 0);
        }
        // 5. write staged regs to the other buffer; 6. barrier
        if (ks < 7) {
            *reinterpret_cast<float4*>(&X[(ks + 1) & 1][wofs0]) = P0;
            *reinterpret_cast<float4*>(&X[(ks + 1) & 1][wofs1]) = P1;
            __syncthreads();
        }
    }

    // --- epilogue: BN + hswish + packed bf16 store (fully coalesced) ---
    #pragma unroll
    for (int fc = 0; fc < 4; fc++)
        #pragma unroll
        for (int reg = 0; reg < 4; reg++) {
            int co = (wcoG + fc) * 16 + gl * 4 + reg;
            float sc = g[co] * rsqrtf(v[co] + EPSB);
            float tt = fmaf(-m[co], sc, b[co]);
            float y0 = hswish(fmaf(acc[fc][0][reg], sc, tt));
            float y1 = hswish(fmaf(acc[fc][1][reg], sc, tt));
            unsigned int pk = pkbf16(y0, y1);
            *reinterpret_cast<unsigned int*>(
                h1b + ((size_t)n * CR + co) * S1 + s0 + wsl + ln16 * 2) = pk;
        }
}

// ---------------------------------------------------------------------------
// Kernel B: depthwise 3x3x3 conv stride 2 pad 1 + BN2 + hswish (bf16 input)
// ---------------------------------------------------------------------------
__global__ __launch_bounds__(256) void dwconv_kernel(
    const unsigned short* __restrict__ h1b, const float* __restrict__ wdw,
    const float* __restrict__ g, const float* __restrict__ b,
    const float* __restrict__ m, const float* __restrict__ v,
    float* __restrict__ h2)
{
    __shared__ float s[T_IN][H_IN][W_IN];
    __shared__ float wl[27];
    int blk = blockIdx.x;
    int n = blk >> 7;
    int c = blk & 127;
    int tid = threadIdx.x;
    const unsigned short* in = h1b + ((size_t)n * CR + c) * S1;

    {
        int e = tid * 8;
        ushort8 u = *reinterpret_cast<const ushort8*>(in + e);
        float* sp = &s[0][0][0] + e;
        #pragma unroll
        for (int i = 0; i < 8; i++)
            sp[i] = __uint_as_float((unsigned int)(unsigned short)u[i] << 16);
    }
    if (tid < 27) wl[tid] = wdw[c * 27 + tid];
    __syncthreads();

    int wo = tid & 7;
    int ho = (tid >> 3) & 7;
    int to = tid >> 6;
    float acc = 0.0f;
    #pragma unroll
    for (int dt = 0; dt < 3; dt++) {
        int ti = 2 * to - 1 + dt;
        if (ti < 0 || ti >= T_IN) continue;
        #pragma unroll
        for (int dh = 0; dh < 3; dh++) {
            int hi = 2 * ho - 1 + dh;
            if (hi < 0 || hi >= H_IN) continue;
            #pragma unroll
            for (int dw = 0; dw < 3; dw++) {
                int wi = 2 * wo - 1 + dw;
                if (wi < 0 || wi >= W_IN) continue;
                acc = fmaf(wl[(dt * 3 + dh) * 3 + dw], s[ti][hi][wi], acc);
            }
        }
    }
    float sc = g[c] * rsqrtf(v[c] + EPSB);
    float y  = fmaf(acc, sc, fmaf(-m[c], sc, b[c]));
    h2[((size_t)n * CR + c) * S2 + tid] = hswish(y);
}

// ---------------------------------------------------------------------------
// Kernel C: 1x1x1 conv 128 -> 128 + BN3 + hswish on [64,128,256]
// ---------------------------------------------------------------------------
#define KC 16
__global__ __launch_bounds__(256) void conv2_kernel(
    const float* __restrict__ h2, const float* __restrict__ w2,
    const float* __restrict__ g, const float* __restrict__ b,
    const float* __restrict__ m, const float* __restrict__ v,
    float* __restrict__ h3)
{
    __shared__ float Xs[KC][64];
    __shared__ float Ws[KC][CR + 4];

    int blk = blockIdx.x;
    int n  = blk >> 2;
    int s0 = (blk & 3) << 6;
    int tid = threadIdx.x;
    int tco = tid >> 3;
    int ts  = tid & 7;
    const float* xn = h2 + (size_t)n * CR * S2;

    float acc[4][8];
    #pragma unroll
    for (int i = 0; i < 4; i++)
        #pragma unroll
        for (int j = 0; j < 8; j++) acc[i][j] = 0.0f;

    for (int k0 = 0; k0 < CR; k0 += KC) {
        {
            int e  = tid * 4;
            int kk = e >> 6;
            int ss = e & 63;
            float4 xv = *reinterpret_cast<const float4*>(xn + (size_t)(k0 + kk) * S2 + s0 + ss);
            *reinterpret_cast<float4*>(&Xs[kk][ss]) = xv;
        }
        #pragma unroll
        for (int r = 0; r < 8; r++) {
            int e  = tid + r * 256;
            int co = e >> 4;
            int kk = e & 15;
            Ws[kk][co] = w2[co * CR + k0 + kk];
        }
        __syncthreads();
        #pragma unroll
        for (int kk = 0; kk < KC; kk++) {
            float a[4], bb[8];
            #pragma unroll
            for (int r = 0; r < 4; r++) a[r] = Ws[kk][tco * 4 + r];
            #pragma unroll
            for (int q = 0; q < 8; q++) bb[q] = Xs[kk][ts * 8 + q];
            #pragma unroll
            for (int r = 0; r < 4; r++)
                #pragma unroll
                for (int q = 0; q < 8; q++)
                    acc[r][q] = fmaf(a[r], bb[q], acc[r][q]);
        }
        __syncthreads();
    }

    #pragma unroll
    for (int r = 0; r < 4; r++) {
        int co = tco * 4 + r;
        float sc = g[co] * rsqrtf(v[co] + EPSB);
        float tt = fmaf(-m[co], sc, b[co]);
        float* o = h3 + ((size_t)n * CR + co) * S2 + s0 + ts * 8;
        float4 o0, o1;
        o0.x = hswish(fmaf(acc[r][0], sc, tt));
        o0.y = hswish(fmaf(acc[r][1], sc, tt));
        o0.z = hswish(fmaf(acc[r][2], sc, tt));
        o0.w = hswish(fmaf(acc[r][3], sc, tt));
        o1.x = hswish(fmaf(acc[r][4], sc, tt));
        o1.y = hswish(fmaf(acc[r][5], sc, tt));
        o1.z = hswish(fmaf(acc[r][6], sc, tt));
        o1.w = hswish(fmaf(acc[r][7], sc, tt));
        *reinterpret_cast<float4*>(o)     = o0;
        *reinterpret_cast<float4*>(o + 4) = o1;
    }
}

// ---------------------------------------------------------------------------
// Kernel D: global mean over 256 spatial positions -> pooled[n][c]
// ---------------------------------------------------------------------------
__global__ __launch_bounds__(256) void pool_kernel(
    const float* __restrict__ h3, float* __restrict__ pooled)
{
    int n = blockIdx.x;
    int tid = threadIdx.x;
    int wave = tid >> 6;
    int lane = tid & 63;
    for (int i = 0; i < 32; i++) {
        int c = wave * 32 + i;
        const float* p = h3 + ((size_t)n * CR + c) * S2;
        float sum = p[lane] + p[lane + 64] + p[lane + 128] + p[lane + 192];
        #pragma unroll
        for (int off = 32; off > 0; off >>= 1)
            sum += __shfl_down(sum, off, 64);
        if (lane == 0) pooled[n * CR + c] = sum * (1.0f / 256.0f);
    }
}

// ---------------------------------------------------------------------------
// Kernel E: head — 1x1 conv 128->6 + BN4 + sigmoid -> ROI boxes [n][6]
// ---------------------------------------------------------------------------
__global__ __launch_bounds__(384) void head_kernel(
    const float* __restrict__ pooled, const float* __restrict__ w3,
    const float* __restrict__ g, const float* __restrict__ b,
    const float* __restrict__ m, const float* __restrict__ v,
    float* __restrict__ boxes)
{
    int tid = threadIdx.x;      // 0..383
    int n = tid / 6;
    int j = tid % 6;
    float acc = 0.0f;
    for (int c = 0; c < CR; c++)
        acc = fmaf(w3[j * CR + c], pooled[n * CR + c], acc);
    float sc = g[j] * rsqrtf(v[j] + EPSB);
    float logit = fmaf(acc, sc, fmaf(-m[j], sc, b[j]));
    float lim = 1.0f / (1.0f + expf(-logit));
    float scale = ((j % 3) == 2) ? 8.0f : 16.0f;
    float val = (j < 3) ? 0.5f * lim * scale : (1.0f - 0.5f * lim) * scale;
    boxes[n * 6 + j] = val;
}

// ---------------------------------------------------------------------------
// Kernel F: 3D ROI align of x.  One block per (n,c); slice in LDS.
// ---------------------------------------------------------------------------
__global__ __launch_bounds__(256) void roi_kernel(
    const float* __restrict__ x, const float* __restrict__ boxes,
    float* __restrict__ out)
{
    __shared__ float s[T_IN][H_IN][W_IN];
    __shared__ float box[6];
    int blk = blockIdx.x;
    int n = blk >> 8;
    int c = blk & 255;
    int tid = threadIdx.x;
    const float* in = x + ((size_t)n * CIN + c) * S1;
    #pragma unroll
    for (int r = 0; r < 2; r++) {
        int e = (tid + r * 256) * 4;
        *reinterpret_cast<float4*>(&s[0][0][0] + e) =
            *reinterpret_cast<const float4*>(in + e);
    }
    if (tid < 6) box[tid] = boxes[n * 6 + tid];
    __syncthreads();

    if (tid < PT * PH * PW) {
        int pw = tid % 7;
        int ph = (tid / 7) % 7;
        int pt = tid / 49;
        float sx = box[0], sy = box[1], st = box[2];
        float bszx = fmaxf(box[3] - sx, 1.0f) * (1.0f / PW);
        float bszy = fmaxf(box[4] - sy, 1.0f) * (1.0f / PH);
        float bszt = fmaxf(box[5] - st, 1.0f) * (1.0f / PT);

        float acc = 0.0f;
        #pragma unroll
        for (int it = 0; it < 2; it++) {
            float tc = st + ((float)(pt * 2 + it) + 0.5f) * 0.5f * bszt;
            tc = fminf(fmaxf(tc, 0.0f), (float)(T_IN - 1));
            int tlo = (int)floorf(tc);
            int thi = min(tlo + 1, T_IN - 1);
            float tw = tc - (float)tlo;
            #pragma unroll
            for (int iy = 0; iy < 2; iy++) {
                float yc = sy + ((float)(ph * 2 + iy) + 0.5f) * 0.5f * bszy;
                yc = fminf(fmaxf(yc, 0.0f), (float)(H_IN - 1));
                int ylo = (int)floorf(yc);
                int yhi = min(ylo + 1, H_IN - 1);
                float yw = yc - (float)ylo;
                #pragma unroll
                for (int ix = 0; ix < 2; ix++) {
                    float xc = sx + ((float)(pw * 2 + ix) + 0.5f) * 0.5f * bszx;
                    xc = fminf(fmaxf(xc, 0.0f), (float)(W_IN - 1));
                    int xlo = (int)floorf(xc);
                    int xhi = min(xlo + 1, W_IN - 1);
                    float xw = xc - (float)xlo;

                    float v00 = s[tlo][ylo][xlo] * (1.0f - xw) + s[tlo][ylo][xhi] * xw;
                    float v01 = s[tlo][yhi][xlo] * (1.0f - xw) + s[tlo][yhi][xhi] * xw;
                    float v10 = s[thi][ylo][xlo] * (1.0f - xw) + s[thi][ylo][xhi] * xw;
                    float v11 = s[thi][yhi][xlo] * (1.0f - xw) + s[thi][yhi][xhi] * xw;
                    float v0 = v00 * (1.0f - yw) + v01 * yw;
                    float v1 = v10 * (1.0f - yw) + v11 * yw;
                    acc += v0 * (1.0f - tw) + v1 * tw;
                }
            }
        }
        out[(((size_t)(n * CIN + c) * PT + pt) * PH + ph) * PW + pw] = acc * 0.125f;
    }
}

// ---------------------------------------------------------------------------
extern "C" void kernel_launch(void* const* d_in, const int* in_sizes, int n_in,
                              void* d_out, int out_size, void* d_ws, size_t ws_size,
                              hipStream_t stream) {
    const float* x   = (const float*)d_in[0];
    const float* w1  = (const float*)d_in[1];
    const float* g1  = (const float*)d_in[2];
    const float* b1  = (const float*)d_in[3];
    const float* m1  = (const float*)d_in[4];
    const float* v1  = (const float*)d_in[5];
    const float* wdw = (const float*)d_in[6];
    const float* g2  = (const float*)d_in[7];
    const float* b2  = (const float*)d_in[8];
    const float* m2  = (const float*)d_in[9];
    const float* v2  = (const float*)d_in[10];
    const float* w2  = (const float*)d_in[11];
    const float* g3  = (const float*)d_in[12];
    const float* b3  = (const float*)d_in[13];
    const float* m3  = (const float*)d_in[14];
    const float* v3  = (const float*)d_in[15];
    const float* w3  = (const float*)d_in[16];
    const float* g4  = (const float*)d_in[17];
    const float* b4  = (const float*)d_in[18];
    const float* m4  = (const float*)d_in[19];
    const float* v4  = (const float*)d_in[20];

    float* ws = (float*)d_ws;
    float* h1     = ws;                                   // used as bf16 (ushort)
    float* h2     = h1 + (size_t)N_BATCH * CR * S1;       //  2,097,152 f
    float* h3     = h2 + (size_t)N_BATCH * CR * S2;       //  2,097,152 f
    float* pooled = h3 + (size_t)N_BATCH * CR * S2;       //      8,192 f
    float* boxes  = pooled + (size_t)N_BATCH * CR;        //        384 f
    unsigned short* h1b = (unsigned short*)h1;            // bf16 h1
    // whi/wlo live in the h3 region (h3 written later by conv2)
    unsigned short* whi = (unsigned short*)h3;            // 32768 u16
    unsigned short* wlo = whi + CR * CIN;                 // 32768 u16

    wsplit_kernel<<<dim3(128), dim3(256), 0, stream>>>(w1, whi, wlo);
    conv1_mfma_kernel<<<dim3(2048), dim3(256), 0, stream>>>(x, whi, wlo, g1, b1, m1, v1, h1b);
    dwconv_kernel<<<dim3(N_BATCH * CR), dim3(256), 0, stream>>>(h1b, wdw, g2, b2, m2, v2, h2);
    conv2_kernel<<<dim3(256), dim3(256), 0, stream>>>(h2, w2, g3, b3, m3, v3, h3);
    pool_kernel<<<dim3(N_BATCH), dim3(256), 0, stream>>>(h3, pooled);
    head_kernel<<<dim3(1), dim3(384), 0, stream>>>(pooled, w3, g4, b4, m4, v4, boxes);
    roi_kernel<<<dim3(N_BATCH * CIN), dim3(256), 0, stream>>>(x, boxes, (float*)d_out);
}

// Round 9
// 124.154 us; speedup vs baseline: 1.6880x; 1.2274x over previous
//
#include <hip/hip_runtime.h>
#include <math.h>

// Problem constants
#define N_BATCH 64
#define CIN 256
#define CR 128
#define T_IN 8
#define H_IN 16
#define W_IN 16
#define S1 2048          // T_IN*H_IN*W_IN
#define T2 4
#define H2 8
#define W2 8
#define S2 256           // T2*H2*W2
#define PT 4
#define PH 7
#define PW 7
#define EPSB 1e-5f

typedef __attribute__((ext_vector_type(8))) short bf16x8;
typedef __attribute__((ext_vector_type(4))) float f32x4;
typedef __attribute__((ext_vector_type(4))) unsigned int u32x4;
typedef __attribute__((ext_vector_type(8))) unsigned short ushort8;

__device__ __forceinline__ float hswish(float y) {
    float c = fminf(fmaxf(y + 3.0f, 0.0f), 6.0f);
    return y * c * (1.0f / 6.0f);
}

__device__ __forceinline__ unsigned int fbits(float x) {
    return __float_as_uint(x);
}

__device__ __forceinline__ unsigned int pkbf16(float lo, float hi) {
    return ((fbits(lo) + 0x8000u) >> 16) | ((fbits(hi) + 0x8000u) & 0xFFFF0000u);
}

// ---------------------------------------------------------------------------
// Prep: split w1 into bf16 hi/lo (fragment-coalesced layout, as v4) and
// zero the pooled-partial buffer (32768 floats, one per thread).
// flat = ((((co>>4)*8 + (k>>5))*4 + ((k>>3)&3))*16 + (co&15))*8 + (k&7)
// ---------------------------------------------------------------------------
__global__ __launch_bounds__(256) void wsplit_kernel(
    const float* __restrict__ w1, unsigned short* __restrict__ whi,
    unsigned short* __restrict__ wlo, float* __restrict__ pp)
{
    int i = blockIdx.x * 256 + threadIdx.x;   // 0..32767
    int co = i >> 8;
    int k  = i & 255;
    float x = w1[i];
    unsigned int bx = fbits(x);
    unsigned int h = (bx + 0x8000u) & 0xFFFF0000u;
    float r = x - __uint_as_float(h);
    int flat = ((((co >> 4) * 8 + (k >> 5)) * 4 + ((k >> 3) & 3)) * 16 + (co & 15)) * 8 + (k & 7);
    whi[flat] = (unsigned short)(h >> 16);
    wlo[flat] = (unsigned short)((fbits(r) + 0x8000u) >> 16);
    pp[i] = 0.0f;   // zero pooled-partial [64n][128co][4sq]
}

// ---------------------------------------------------------------------------
// Kernel A v5: 1x1x1 conv 256->128 + BN1 + hswish, split-bf16 MFMA.
// Tile [128co][64s], 4 waves (2 co-halves x 2 s-halves), wave = 64co x 32s.
// LDS holds PRE-PACKED bf16 B-fragments (staging threads convert+pack), so
// the inner loop is 2 ds_read_b128 + 8 W dwordx4 + 16 MFMA per wave per ks.
// B-frag slot (g, h, e, ln) holds k = g*8..+7 (bf16 pairs) at s = h*32+2*ln+e.
// ---------------------------------------------------------------------------
#define BFIDX(g, h, e, ln) (((((g) * 2 + (h)) * 2 + (e)) * 16 + (ln)) * 4)

__global__ __launch_bounds__(256, 5) void conv1_mfma_kernel(
    const float* __restrict__ x,
    const unsigned short* __restrict__ whi, const unsigned short* __restrict__ wlo,
    const float* __restrict__ g, const float* __restrict__ b,
    const float* __restrict__ m, const float* __restrict__ v,
    unsigned short* __restrict__ h1b)
{
    __shared__ unsigned int Bf[2][1024];   // 2 x 4KB

    int blk = blockIdx.x;
    int n  = blk >> 5;
    int s0 = (blk & 31) << 6;
    int tid = threadIdx.x;
    int wave = tid >> 6;
    int lane = tid & 63;
    int gl   = lane >> 4;          // 0..3 (k-octet)
    int ln16 = lane & 15;
    int hw   = wave & 1;           // wave's s-half (32 s)
    int wcoG = (wave >> 1) * 4;    // co-group base (16-co units)

    // staging coords: thread covers k-octet sg, column s (one s per thread)
    int sg = tid >> 6;             // 0..3 (k-octet within 32-k step)
    int sc = tid & 63;             // s column 0..63
    int sh = sc >> 5;              // LDS h
    int se = sc & 1;               // LDS e
    int sl = (sc & 31) >> 1;       // LDS ln
    int wslot = BFIDX(sg, sh, se, sl);
    const float* xg = x + (size_t)n * CIN * S1 + s0 + sc;

    f32x4 acc[4][2];
    #pragma unroll
    for (int i = 0; i < 4; i++) {
        acc[i][0] = (f32x4){0.f, 0.f, 0.f, 0.f};
        acc[i][1] = (f32x4){0.f, 0.f, 0.f, 0.f};
    }

    // --- prologue: stage ks=0 ---
    {
        float val[8];
        #pragma unroll
        for (int j = 0; j < 8; j++)
            val[j] = xg[(size_t)(sg * 8 + j) * S1];
        u32x4 w;
        #pragma unroll
        for (int p = 0; p < 4; p++)
            w[p] = pkbf16(val[2 * p], val[2 * p + 1]);
        *reinterpret_cast<u32x4*>(&Bf[0][wslot]) = w;
    }
    __syncthreads();

    #pragma unroll
    for (int ks = 0; ks < 8; ks++) {
        // 1. issue next K-step's x loads
        float val[8];
        if (ks < 7) {
            #pragma unroll
            for (int j = 0; j < 8; j++)
                val[j] = xg[(size_t)((ks + 1) * 32 + sg * 8 + j) * S1];
        }
        // 2. B fragments: one ds_read_b128 each
        union { u32x4 u; bf16x8 bv; } B0, B1;
        B0.u = *reinterpret_cast<const u32x4*>(&Bf[ks & 1][BFIDX(gl, hw, 0, ln16)]);
        B1.u = *reinterpret_cast<const u32x4*>(&Bf[ks & 1][BFIDX(gl, hw, 1, ln16)]);
        // 3. W hi fragments + 8 MFMA
        {
            bf16x8 Ah[4];
            #pragma unroll
            for (int fc = 0; fc < 4; fc++) {
                int off = ((((wcoG + fc) * 8 + ks) * 4 + gl) * 16 + ln16) * 8;
                Ah[fc] = *reinterpret_cast<const bf16x8*>(whi + off);
            }
            #pragma unroll
            for (int fc = 0; fc < 4; fc++) {
                acc[fc][0] = __builtin_amdgcn_mfma_f32_16x16x32_bf16(Ah[fc], B0.bv, acc[fc][0], 0, 0, 0);
                acc[fc][1] = __builtin_amdgcn_mfma_f32_16x16x32_bf16(Ah[fc], B1.bv, acc[fc][1], 0, 0, 0);
            }
        }
        // 4. W lo fragments + 8 MFMA
        {
            bf16x8 Al[4];
            #pragma unroll
            for (int fc = 0; fc < 4; fc++) {
                int off = ((((wcoG + fc) * 8 + ks) * 4 + gl) * 16 + ln16) * 8;
                Al[fc] = *reinterpret_cast<const bf16x8*>(wlo + off);
            }
            #pragma unroll
            for (int fc = 0; fc < 4; fc++) {
                acc[fc][0] = __builtin_amdgcn_mfma_f32_16x16x32_bf16(Al[fc], B0.bv, acc[fc][0], 0, 0, 0);
                acc[fc][1] = __builtin_amdgcn_mfma_f32_16x16x32_bf16(Al[fc], B1.bv, acc[fc][1], 0, 0, 0);
            }
        }
        // 5. pack + write next buffer, barrier
        if (ks < 7) {
            u32x4 w;
            #pragma unroll
            for (int p = 0; p < 4; p++)
                w[p] = pkbf16(val[2 * p], val[2 * p + 1]);
            *reinterpret_cast<u32x4*>(&Bf[(ks + 1) & 1][wslot]) = w;
            __syncthreads();
        }
    }

    // --- epilogue: BN + hswish + packed bf16 store (e0/e1 = even/odd s) ---
    #pragma unroll
    for (int fc = 0; fc < 4; fc++)
        #pragma unroll
        for (int reg = 0; reg < 4; reg++) {
            int co = (wcoG + fc) * 16 + gl * 4 + reg;
            float sc_ = g[co] * rsqrtf(v[co] + EPSB);
            float tt = fmaf(-m[co], sc_, b[co]);
            float y0 = hswish(fmaf(acc[fc][0][reg], sc_, tt));
            float y1 = hswish(fmaf(acc[fc][1][reg], sc_, tt));
            unsigned int pk = pkbf16(y0, y1);
            *reinterpret_cast<unsigned int*>(
                h1b + ((size_t)n * CR + co) * S1 + s0 + hw * 32 + ln16 * 2) = pk;
        }
}

// ---------------------------------------------------------------------------
// Kernel B: depthwise 3x3x3 conv stride 2 pad 1 + BN2 + hswish (bf16 input)
// ---------------------------------------------------------------------------
__global__ __launch_bounds__(256) void dwconv_kernel(
    const unsigned short* __restrict__ h1b, const float* __restrict__ wdw,
    const float* __restrict__ g, const float* __restrict__ b,
    const float* __restrict__ m, const float* __restrict__ v,
    float* __restrict__ h2)
{
    __shared__ float s[T_IN][H_IN][W_IN];
    __shared__ float wl[27];
    int blk = blockIdx.x;
    int n = blk >> 7;
    int c = blk & 127;
    int tid = threadIdx.x;
    const unsigned short* in = h1b + ((size_t)n * CR + c) * S1;

    {
        int e = tid * 8;
        ushort8 u = *reinterpret_cast<const ushort8*>(in + e);
        float* sp = &s[0][0][0] + e;
        #pragma unroll
        for (int i = 0; i < 8; i++)
            sp[i] = __uint_as_float((unsigned int)(unsigned short)u[i] << 16);
    }
    if (tid < 27) wl[tid] = wdw[c * 27 + tid];
    __syncthreads();

    int wo = tid & 7;
    int ho = (tid >> 3) & 7;
    int to = tid >> 6;
    float acc = 0.0f;
    #pragma unroll
    for (int dt = 0; dt < 3; dt++) {
        int ti = 2 * to - 1 + dt;
        if (ti < 0 || ti >= T_IN) continue;
        #pragma unroll
        for (int dh = 0; dh < 3; dh++) {
            int hi = 2 * ho - 1 + dh;
            if (hi < 0 || hi >= H_IN) continue;
            #pragma unroll
            for (int dw = 0; dw < 3; dw++) {
                int wi = 2 * wo - 1 + dw;
                if (wi < 0 || wi >= W_IN) continue;
                acc = fmaf(wl[(dt * 3 + dh) * 3 + dw], s[ti][hi][wi], acc);
            }
        }
    }
    float sc = g[c] * rsqrtf(v[c] + EPSB);
    float y  = fmaf(acc, sc, fmaf(-m[c], sc, b[c]));
    h2[((size_t)n * CR + c) * S2 + tid] = hswish(y);
}

// ---------------------------------------------------------------------------
// Kernel C: 1x1x1 conv 128 -> 128 + BN3 + hswish, FUSED global-mean partials.
// h3 is never materialized; each block writes per-co partial sums over its
// 64-s quarter to pp[n][co][sq].
// ---------------------------------------------------------------------------
#define KC 16
__global__ __launch_bounds__(256) void conv2_kernel(
    const float* __restrict__ h2, const float* __restrict__ w2,
    const float* __restrict__ g, const float* __restrict__ b,
    const float* __restrict__ m, const float* __restrict__ v,
    float* __restrict__ pp)
{
    __shared__ float Xs[KC][64];
    __shared__ float Ws[KC][CR + 4];

    int blk = blockIdx.x;
    int n  = blk >> 2;
    int sq = blk & 3;
    int s0 = sq << 6;
    int tid = threadIdx.x;
    int tco = tid >> 3;
    int ts  = tid & 7;
    const float* xn = h2 + (size_t)n * CR * S2;

    float acc[4][8];
    #pragma unroll
    for (int i = 0; i < 4; i++)
        #pragma unroll
        for (int j = 0; j < 8; j++) acc[i][j] = 0.0f;

    for (int k0 = 0; k0 < CR; k0 += KC) {
        {
            int e  = tid * 4;
            int kk = e >> 6;
            int ss = e & 63;
            float4 xv = *reinterpret_cast<const float4*>(xn + (size_t)(k0 + kk) * S2 + s0 + ss);
            *reinterpret_cast<float4*>(&Xs[kk][ss]) = xv;
        }
        #pragma unroll
        for (int r = 0; r < 8; r++) {
            int e  = tid + r * 256;
            int co = e >> 4;
            int kk = e & 15;
            Ws[kk][co] = w2[co * CR + k0 + kk];
        }
        __syncthreads();
        #pragma unroll
        for (int kk = 0; kk < KC; kk++) {
            float a[4], bb[8];
            #pragma unroll
            for (int r = 0; r < 4; r++) a[r] = Ws[kk][tco * 4 + r];
            #pragma unroll
            for (int q = 0; q < 8; q++) bb[q] = Xs[kk][ts * 8 + q];
            #pragma unroll
            for (int r = 0; r < 4; r++)
                #pragma unroll
                for (int q = 0; q < 8; q++)
                    acc[r][q] = fmaf(a[r], bb[q], acc[r][q]);
        }
        __syncthreads();
    }

    #pragma unroll
    for (int r = 0; r < 4; r++) {
        int co = tco * 4 + r;
        float sc = g[co] * rsqrtf(v[co] + EPSB);
        float tt = fmaf(-m[co], sc, b[co]);
        float psum = 0.0f;
        #pragma unroll
        for (int q = 0; q < 8; q++)
            psum += hswish(fmaf(acc[r][q], sc, tt));
        // reduce over the 8 ts-lanes sharing (tco)
        #pragma unroll
        for (int off = 4; off > 0; off >>= 1)
            psum += __shfl_down(psum, off, 8);
        if (ts == 0)
            pp[((size_t)n * CR + co) * 4 + sq] = psum;
    }
}

// ---------------------------------------------------------------------------
// Kernel E: head — pooled mean from partials, 1x1 conv 128->6 + BN4 +
// sigmoid -> ROI boxes [n][6].  One block per n.
// ---------------------------------------------------------------------------
__global__ __launch_bounds__(128) void head_kernel(
    const float* __restrict__ pp, const float* __restrict__ w3,
    const float* __restrict__ g, const float* __restrict__ b,
    const float* __restrict__ m, const float* __restrict__ v,
    float* __restrict__ boxes)
{
    __shared__ float red[2];
    int n = blockIdx.x;
    int c = threadIdx.x;          // 0..127
    int wave = c >> 6, lane = c & 63;
    const float* p = pp + ((size_t)n * CR + c) * 4;
    float pc = (p[0] + p[1] + p[2] + p[3]) * (1.0f / 256.0f);

    for (int j = 0; j < 6; j++) {
        float t = w3[j * CR + c] * pc;
        #pragma unroll
        for (int off = 32; off > 0; off >>= 1)
            t += __shfl_down(t, off, 64);
        if (lane == 0) red[wave] = t;
        __syncthreads();
        if (c == 0) {
            float acc = red[0] + red[1];
            float sc = g[j] * rsqrtf(v[j] + EPSB);
            float logit = fmaf(acc, sc, fmaf(-m[j], sc, b[j]));
            float lim = 1.0f / (1.0f + expf(-logit));
            float scale = ((j % 3) == 2) ? 8.0f : 16.0f;
            float val = (j < 3) ? 0.5f * lim * scale : (1.0f - 0.5f * lim) * scale;
            boxes[n * 6 + j] = val;
        }
        __syncthreads();
    }
}

// ---------------------------------------------------------------------------
// Kernel F: 3D ROI align of x.  One block per (n,c); slice in LDS.
// ---------------------------------------------------------------------------
__global__ __launch_bounds__(256) void roi_kernel(
    const float* __restrict__ x, const float* __restrict__ boxes,
    float* __restrict__ out)
{
    __shared__ float s[T_IN][H_IN][W_IN];
    __shared__ float box[6];
    int blk = blockIdx.x;
    int n = blk >> 8;
    int c = blk & 255;
    int tid = threadIdx.x;
    const float* in = x + ((size_t)n * CIN + c) * S1;
    #pragma unroll
    for (int r = 0; r < 2; r++) {
        int e = (tid + r * 256) * 4;
        *reinterpret_cast<float4*>(&s[0][0][0] + e) =
            *reinterpret_cast<const float4*>(in + e);
    }
    if (tid < 6) box[tid] = boxes[n * 6 + tid];
    __syncthreads();

    if (tid < PT * PH * PW) {
        int pw = tid % 7;
        int ph = (tid / 7) % 7;
        int pt = tid / 49;
        float sx = box[0], sy = box[1], st = box[2];
        float bszx = fmaxf(box[3] - sx, 1.0f) * (1.0f / PW);
        float bszy = fmaxf(box[4] - sy, 1.0f) * (1.0f / PH);
        float bszt = fmaxf(box[5] - st, 1.0f) * (1.0f / PT);

        float acc = 0.0f;
        #pragma unroll
        for (int it = 0; it < 2; it++) {
            float tc = st + ((float)(pt * 2 + it) + 0.5f) * 0.5f * bszt;
            tc = fminf(fmaxf(tc, 0.0f), (float)(T_IN - 1));
            int tlo = (int)floorf(tc);
            int thi = min(tlo + 1, T_IN - 1);
            float tw = tc - (float)tlo;
            #pragma unroll
            for (int iy = 0; iy < 2; iy++) {
                float yc = sy + ((float)(ph * 2 + iy) + 0.5f) * 0.5f * bszy;
                yc = fminf(fmaxf(yc, 0.0f), (float)(H_IN - 1));
                int ylo = (int)floorf(yc);
                int yhi = min(ylo + 1, H_IN - 1);
                float yw = yc - (float)ylo;
                #pragma unroll
                for (int ix = 0; ix < 2; ix++) {
                    float xc = sx + ((float)(pw * 2 + ix) + 0.5f) * 0.5f * bszx;
                    xc = fminf(fmaxf(xc, 0.0f), (float)(W_IN - 1));
                    int xlo = (int)floorf(xc);
                    int xhi = min(xlo + 1, W_IN - 1);
                    float xw = xc - (float)xlo;

                    float v00 = s[tlo][ylo][xlo] * (1.0f - xw) + s[tlo][ylo][xhi] * xw;
                    float v01 = s[tlo][yhi][xlo] * (1.0f - xw) + s[tlo][yhi][xhi] * xw;
                    float v10 = s[thi][ylo][xlo] * (1.0f - xw) + s[thi][ylo][xhi] * xw;
                    float v11 = s[thi][yhi][xlo] * (1.0f - xw) + s[thi][yhi][xhi] * xw;
                    float v0 = v00 * (1.0f - yw) + v01 * yw;
                    float v1 = v10 * (1.0f - yw) + v11 * yw;
                    acc += v0 * (1.0f - tw) + v1 * tw;
                }
            }
        }
        out[(((size_t)(n * CIN + c) * PT + pt) * PH + ph) * PW + pw] = acc * 0.125f;
    }
}

// ---------------------------------------------------------------------------
extern "C" void kernel_launch(void* const* d_in, const int* in_sizes, int n_in,
                              void* d_out, int out_size, void* d_ws, size_t ws_size,
                              hipStream_t stream) {
    const float* x   = (const float*)d_in[0];
    const float* w1  = (const float*)d_in[1];
    const float* g1  = (const float*)d_in[2];
    const float* b1  = (const float*)d_in[3];
    const float* m1  = (const float*)d_in[4];
    const float* v1  = (const float*)d_in[5];
    const float* wdw = (const float*)d_in[6];
    const float* g2  = (const float*)d_in[7];
    const float* b2  = (const float*)d_in[8];
    const float* m2  = (const float*)d_in[9];
    const float* v2  = (const float*)d_in[10];
    const float* w2  = (const float*)d_in[11];
    const float* g3  = (const float*)d_in[12];
    const float* b3  = (const float*)d_in[13];
    const float* m3  = (const float*)d_in[14];
    const float* v3  = (const float*)d_in[15];
    const float* w3  = (const float*)d_in[16];
    const float* g4  = (const float*)d_in[17];
    const float* b4  = (const float*)d_in[18];
    const float* m4  = (const float*)d_in[19];
    const float* v4  = (const float*)d_in[20];

    float* ws = (float*)d_ws;
    float* h1     = ws;                                   // bf16 h1 (ushort)
    float* h2     = h1 + (size_t)N_BATCH * CR * S1;       // 2,097,152 f
    float* h3     = h2 + (size_t)N_BATCH * CR * S2;       // region reused for whi/wlo
    float* pp     = h3 + (size_t)N_BATCH * CR * S2;       // 32,768 f pooled partials
    float* boxes  = pp + (size_t)N_BATCH * CR * 4;        // 384 f
    unsigned short* h1b = (unsigned short*)h1;
    unsigned short* whi = (unsigned short*)h3;            // 32768 u16
    unsigned short* wlo = whi + CR * CIN;                 // 32768 u16

    wsplit_kernel<<<dim3(128), dim3(256), 0, stream>>>(w1, whi, wlo, pp);
    conv1_mfma_kernel<<<dim3(2048), dim3(256), 0, stream>>>(x, whi, wlo, g1, b1, m1, v1, h1b);
    dwconv_kernel<<<dim3(N_BATCH * CR), dim3(256), 0, stream>>>(h1b, wdw, g2, b2, m2, v2, h2);
    conv2_kernel<<<dim3(256), dim3(256), 0, stream>>>(h2, w2, g3, b3, m3, v3, pp);
    head_kernel<<<dim3(N_BATCH), dim3(128), 0, stream>>>(pp, w3, g4, b4, m4, v4, boxes);
    roi_kernel<<<dim3(N_BATCH * CIN), dim3(256), 0, stream>>>(x, boxes, (float*)d_out);
}